// Round 2
// baseline (1669.267 us; speedup 1.0000x reference)
//
#include <hip/hip_runtime.h>
#include <stdint.h>

#define N_TOK 32768
#define D_IN  512
#define H_DIM 2048
#define O_DIM 512
#define N_EXP 8
#define BM    128
#define BH    128
#define MAX_TILES 264   // sum ceil(cnt_e/128) <= 256 + 7

typedef __bf16 bf16x8 __attribute__((ext_vector_type(8)));
typedef float  f32x4  __attribute__((ext_vector_type(4)));

struct alignas(8) us4 { unsigned short x, y, z, w; };

__device__ __forceinline__ unsigned short f2bf(float f) {
  union { float f; unsigned u; } v; v.f = f;
  unsigned r = v.u + 0x7FFFu + ((v.u >> 16) & 1u);  // round-to-nearest-even
  return (unsigned short)(r >> 16);
}

__device__ __forceinline__ int hswz(int row) {
  return (((row ^ (row >> 3)) & 7) << 4);
}

// ---------------- init: zero counts ----------------
__global__ void k_init(int* counts) {
  if (threadIdx.x < N_EXP) counts[threadIdx.x] = 0;
}

// ---------------- weight convert + transpose to bf16 ----------------
// W (E, R, C) fp32 row-major  ->  WT (E, C, R) bf16
__global__ void k_transpose(const float* __restrict__ W, unsigned short* __restrict__ WT,
                            int R, int C) {
  __shared__ unsigned short tile[64][72];
  int e = blockIdx.y;
  const float* src = W + (size_t)e * R * C;
  unsigned short* dst = WT + (size_t)e * R * C;
  int tilesC = C >> 6;
  int tc = (blockIdx.x % tilesC) << 6;
  int tr = (blockIdx.x / tilesC) << 6;
  int tid = threadIdx.x;
  int rq = tid >> 4;      // 0..15
  int cq = tid & 15;      // 0..15
#pragma unroll
  for (int q = 0; q < 4; ++q) {
    int r = q * 16 + rq;
    float4 v = *(const float4*)(src + (size_t)(tr + r) * C + tc + cq * 4);
    us4 b;
    b.x = f2bf(v.x); b.y = f2bf(v.y); b.z = f2bf(v.z); b.w = f2bf(v.w);
    *(us4*)&tile[r][cq * 4] = b;
  }
  __syncthreads();
#pragma unroll
  for (int q = 0; q < 4; ++q) {
    int cc = q * 16 + rq;   // output row (= original col)
    int rr = cq * 4;        // output cols (= original rows)
    us4 o;
    o.x = tile[rr + 0][cc]; o.y = tile[rr + 1][cc];
    o.z = tile[rr + 2][cc]; o.w = tile[rr + 3][cc];
    *(us4*)(dst + (size_t)(tc + cc) * R + tr + rr) = o;
  }
}

// ---------------- router: fp32, wave per token ----------------
__global__ void k_router(const float* __restrict__ x, const float* __restrict__ Wr,
                         const float* __restrict__ br, int* __restrict__ expert_id,
                         int* __restrict__ counts) {
  int token = blockIdx.x * 4 + (threadIdx.x >> 6);
  int lane  = threadIdx.x & 63;
  const float* xr = x + (size_t)token * D_IN;
  float acc[N_EXP];
#pragma unroll
  for (int e = 0; e < N_EXP; ++e) acc[e] = 0.f;
#pragma unroll
  for (int j = 0; j < 2; ++j) {
    int i0 = lane * 8 + j * 4;
    float4 xv = *(const float4*)(xr + i0);
    float xs[4] = {xv.x, xv.y, xv.z, xv.w};
#pragma unroll
    for (int u = 0; u < 4; ++u) {
      const float4* wr = (const float4*)(Wr + (size_t)(i0 + u) * N_EXP);
      float4 w0 = wr[0], w1 = wr[1];
      acc[0] += xs[u] * w0.x; acc[1] += xs[u] * w0.y;
      acc[2] += xs[u] * w0.z; acc[3] += xs[u] * w0.w;
      acc[4] += xs[u] * w1.x; acc[5] += xs[u] * w1.y;
      acc[6] += xs[u] * w1.z; acc[7] += xs[u] * w1.w;
    }
  }
#pragma unroll
  for (int off = 32; off > 0; off >>= 1) {
#pragma unroll
    for (int e = 0; e < N_EXP; ++e) acc[e] += __shfl_xor(acc[e], off, 64);
  }
  if (lane == 0) {
    float best = acc[0] + br[0]; int bi = 0;
#pragma unroll
    for (int e = 1; e < N_EXP; ++e) {
      float v = acc[e] + br[e];
      if (v > best) { best = v; bi = e; }   // strict > : first max wins (matches top_k)
    }
    expert_id[token] = bi;
    atomicAdd(&counts[bi], 1);
  }
}

// ---------------- scan: offsets + cursors + balanced tile table ----------------
// table slot i prefers expert i%8 so consecutive blocks (round-robin XCDs)
// keep a stable expert<->XCD mapping -> each XCD's L2 caches one expert's weights.
__global__ void k_scan(const int* __restrict__ counts, int* __restrict__ offsets,
                       int* __restrict__ cursor, int2* __restrict__ table) {
  if (threadIdx.x == 0) {
    int s = 0, tc[N_EXP], done[N_EXP];
    for (int e = 0; e < N_EXP; ++e) {
      offsets[e] = s; cursor[e] = s; s += counts[e];
      tc[e] = (counts[e] + BM - 1) / BM; done[e] = 0;
    }
    for (int i = 0; i < MAX_TILES; ++i) {
      int e = -1, pref = i & 7;
      if (done[pref] < tc[pref]) e = pref;
      else {
        int bv = 0;
        for (int j = 0; j < N_EXP; ++j) {
          int r = tc[j] - done[j];
          if (r > bv) { bv = r; e = j; }
        }
      }
      if (e >= 0) { table[i] = make_int2(e, done[e]); done[e]++; }
      else        { table[i] = make_int2(-1, -1); }
    }
  }
}

// ---------------- scatter tokens into per-expert lists ----------------
__global__ void k_scatter(const int* __restrict__ expert_id, int* __restrict__ cursor,
                          int* __restrict__ idx_list) {
  int i = blockIdx.x * 256 + threadIdx.x;
  int e = expert_id[i];
  int pos = atomicAdd(&cursor[e], 1);
  idx_list[pos] = i;
}

// ---------------- fused MoE MLP ----------------
// 128-token tile per block, 8 waves as 2(row) x 4(col), 160 KB LDS, 1 block/CU.
__launch_bounds__(512, 2)
__global__ void k_moe(const float* __restrict__ x,
                      const unsigned short* __restrict__ W1T,   // (E, H, D) bf16
                      const unsigned short* __restrict__ W2T,   // (E, O, H) bf16
                      const float* __restrict__ b1, const float* __restrict__ b2,
                      const int* __restrict__ counts, const int* __restrict__ offsets,
                      const int2* __restrict__ table, const int* __restrict__ idx_list,
                      float* __restrict__ out) {
  int2 et = table[blockIdx.x];
  int e = et.x;
  if (e < 0) return;
  int t = et.y;
  int cnt = counts[e];
  int base   = offsets[e] + t * BM;
  int mvalid = min(BM, cnt - t * BM);

  __shared__ __align__(16) unsigned short Xs[BM * D_IN];  // 128 KB, swizzled ((row&7)<<4)
  __shared__ __align__(16) unsigned short Hs[BM * BH];    //  32 KB, swizzled hswz(row)

  int tid  = threadIdx.x;
  int wave = tid >> 6;
  int lane = tid & 63;
  int l15  = lane & 15;
  int l4   = lane >> 4;
  int wr   = wave >> 2;   // 0..1 : row group (64 rows)
  int wc   = wave & 3;    // 0..3 : col group

  // ---- stage X tile (gather, fp32 -> bf16, swizzled): 16 rows per wave ----
#pragma unroll 4
  for (int rr = 0; rr < 16; ++rr) {
    int row = wave * 16 + rr;
    int tok = idx_list[base + min(row, mvalid - 1)];
    const float4* src = (const float4*)(x + (size_t)tok * D_IN);
#pragma unroll
    for (int p = 0; p < 2; ++p) {
      float4 v = src[p * 64 + lane];
      us4 b;
      b.x = f2bf(v.x); b.y = f2bf(v.y); b.z = f2bf(v.z); b.w = f2bf(v.w);
      int baddr = row * (D_IN * 2) + p * 512 + lane * 8;
      baddr ^= ((row & 7) << 4);
      *(us4*)((char*)Xs + baddr) = b;
    }
  }
  __syncthreads();

  f32x4 acc2[4][8];
#pragma unroll
  for (int a = 0; a < 4; ++a)
#pragma unroll
    for (int b = 0; b < 8; ++b) acc2[a][b] = (f32x4){0.f, 0.f, 0.f, 0.f};

  const unsigned short* w1base = W1T + ((size_t)e * H_DIM + wc * 32 + l15) * D_IN + l4 * 8;
  const unsigned short* w2base = W2T + ((size_t)e * O_DIM + wc * 128 + l15) * H_DIM + l4 * 8;
  const float* b1base = b1 + (size_t)e * H_DIM + wc * 32 + l15;

  for (int ch = 0; ch < H_DIM / BH; ++ch) {
    // ---- GEMM1: wave computes H[wr*64 .. +64, ch*128 + wc*32 .. +32) ----
    f32x4 acc1[2][4];
#pragma unroll
    for (int c = 0; c < 2; ++c)
#pragma unroll
      for (int r = 0; r < 4; ++r) acc1[c][r] = (f32x4){0.f, 0.f, 0.f, 0.f};

    const unsigned short* w1p = w1base + (size_t)(ch * BH) * D_IN;
#pragma unroll
    for (int ks = 0; ks < D_IN / 32; ++ks) {
      bf16x8 bf0 = *(const bf16x8*)(w1p + ks * 32);
      bf16x8 bf1 = *(const bf16x8*)(w1p + (size_t)16 * D_IN + ks * 32);
#pragma unroll
      for (int rf = 0; rf < 4; ++rf) {
        int arow  = wr * 64 + rf * 16 + l15;
        int baddr = (arow * (D_IN * 2) + ks * 64 + l4 * 16) ^ ((arow & 7) << 4);
        bf16x8 af = *(const bf16x8*)((const char*)Xs + baddr);
        acc1[0][rf] = __builtin_amdgcn_mfma_f32_16x16x32_bf16(af, bf0, acc1[0][rf], 0, 0, 0);
        acc1[1][rf] = __builtin_amdgcn_mfma_f32_16x16x32_bf16(af, bf1, acc1[1][rf], 0, 0, 0);
      }
    }

    // bias + relu + bf16 -> Hs (swizzled)
    float b1v0 = b1base[ch * BH];
    float b1v1 = b1base[ch * BH + 16];
#pragma unroll
    for (int cf = 0; cf < 2; ++cf) {
      float bv = cf ? b1v1 : b1v0;
#pragma unroll
      for (int rf = 0; rf < 4; ++rf) {
#pragma unroll
        for (int j = 0; j < 4; ++j) {
          float v = fmaxf(acc1[cf][rf][j] + bv, 0.f);
          int row = wr * 64 + rf * 16 + l4 * 4 + j;
          int col = wc * 32 + cf * 16 + l15;
          int haddr = (row * (BH * 2) + col * 2) ^ hswz(row);
          *(unsigned short*)((char*)Hs + haddr) = f2bf(v);
        }
      }
    }
    __syncthreads();

    // ---- GEMM2: wave computes O[wr*64 .. +64, wc*128 .. +128) += Hs @ W2T-slice ----
    const unsigned short* w2p = w2base + ch * BH;
#pragma unroll
    for (int ks2 = 0; ks2 < BH / 32; ++ks2) {
      bf16x8 af[4];
#pragma unroll
      for (int rf = 0; rf < 4; ++rf) {
        int row = wr * 64 + rf * 16 + l15;
        int baddr = (row * (BH * 2) + ks2 * 64 + l4 * 16) ^ hswz(row);
        af[rf] = *(const bf16x8*)((const char*)Hs + baddr);
      }
#pragma unroll
      for (int cf = 0; cf < 8; ++cf) {
        bf16x8 bf = *(const bf16x8*)(w2p + (size_t)cf * 16 * H_DIM + ks2 * 32);
#pragma unroll
        for (int rf = 0; rf < 4; ++rf)
          acc2[rf][cf] = __builtin_amdgcn_mfma_f32_16x16x32_bf16(af[rf], bf, acc2[rf][cf], 0, 0, 0);
      }
    }
    __syncthreads();
  }

  // ---- epilogue: bias + scatter store (fp32) ----
#pragma unroll
  for (int cf = 0; cf < 8; ++cf) {
    int col = wc * 128 + cf * 16 + l15;
    float b2v = b2[(size_t)e * O_DIM + col];
#pragma unroll
    for (int rf = 0; rf < 4; ++rf) {
#pragma unroll
      for (int j = 0; j < 4; ++j) {
        int row = wr * 64 + rf * 16 + l4 * 4 + j;
        if (row < mvalid) {
          int tok = idx_list[base + row];
          out[(size_t)tok * O_DIM + col] = acc2[rf][cf][j] + b2v;
        }
      }
    }
  }
}

// ---------------- launch ----------------
extern "C" void kernel_launch(void* const* d_in, const int* in_sizes, int n_in,
                              void* d_out, int out_size, void* d_ws, size_t ws_size,
                              hipStream_t stream) {
  const float* x  = (const float*)d_in[0];
  const float* Wr = (const float*)d_in[1];
  const float* br = (const float*)d_in[2];
  const float* W1 = (const float*)d_in[3];
  const float* b1 = (const float*)d_in[4];
  const float* W2 = (const float*)d_in[5];
  const float* b2 = (const float*)d_in[6];
  float* out = (float*)d_out;

  char* ws = (char*)d_ws;
  int*  counts    = (int*)(ws + 0);
  int*  offsets   = (int*)(ws + 64);
  int*  cursor    = (int*)(ws + 128);
  int2* table     = (int2*)(ws + 256);                 // 264 * 8 B
  int*  expert_id = (int*)(ws + 4096);                 // 128 KB
  int*  idx_list  = (int*)(ws + 4096 + N_TOK * 4);     // 128 KB
  unsigned short* W1T = (unsigned short*)(ws + 4096 + 2 * (size_t)N_TOK * 4 + 256); // 16 MB
  unsigned short* W2T = W1T + (size_t)N_EXP * H_DIM * D_IN;                         // 16 MB

  k_init<<<1, 64, 0, stream>>>(counts);
  k_transpose<<<dim3(256, N_EXP), 256, 0, stream>>>(W1, W1T, D_IN, H_DIM);
  k_transpose<<<dim3(256, N_EXP), 256, 0, stream>>>(W2, W2T, H_DIM, O_DIM);
  k_router<<<N_TOK / 4, 256, 0, stream>>>(x, Wr, br, expert_id, counts);
  k_scan<<<1, 64, 0, stream>>>(counts, offsets, cursor, table);
  k_scatter<<<N_TOK / 256, 256, 0, stream>>>(expert_id, cursor, idx_list);
  k_moe<<<MAX_TILES, 512, 0, stream>>>(x, W1T, W2T, b1, b2,
                                       counts, offsets, table, idx_list, out);
}

// Round 3
// 727.447 us; speedup vs baseline: 2.2947x; 2.2947x over previous
//
#include <hip/hip_runtime.h>
#include <stdint.h>

#define N_TOK 32768
#define D_IN  512
#define H_DIM 2048
#define O_DIM 512
#define N_EXP 8
#define BM    256
#define BN    256
#define BK    64
#define MAX_TILES 144   // 32768/256 = 128 full tiles + <=7 pad + slack

typedef __bf16 bf16x8 __attribute__((ext_vector_type(8)));
typedef float  f32x4  __attribute__((ext_vector_type(4)));

struct alignas(8) us4 { unsigned short x, y, z, w; };

__device__ __forceinline__ unsigned short f2bf(float f) {
  union { float f; unsigned u; } v; v.f = f;
  unsigned r = v.u + 0x7FFFu + ((v.u >> 16) & 1u);  // round-to-nearest-even
  return (unsigned short)(r >> 16);
}

// async global->LDS, 16B per lane; LDS dest must be wave-uniform base (+lane*16 by HW)
__device__ __forceinline__ void gll16(const void* src, void* lds_dst) {
  __builtin_amdgcn_global_load_lds(
      (const __attribute__((address_space(1))) void*)src,
      (__attribute__((address_space(3))) void*)lds_dst, 16, 0, 0);
}

// ---------------- init ----------------
__global__ void k_init(int* counts) {
  if (threadIdx.x < N_EXP) counts[threadIdx.x] = 0;
}

// ---------------- weight convert + transpose to bf16 ----------------
// W (E, R, C) fp32 row-major  ->  WT (E, C, R) bf16
__global__ void k_transpose(const float* __restrict__ W, unsigned short* __restrict__ WT,
                            int R, int C) {
  __shared__ unsigned short tile[64][72];
  int e = blockIdx.y;
  const float* src = W + (size_t)e * R * C;
  unsigned short* dst = WT + (size_t)e * R * C;
  int tilesC = C >> 6;
  int tc = (blockIdx.x % tilesC) << 6;
  int tr = (blockIdx.x / tilesC) << 6;
  int tid = threadIdx.x;
  int rq = tid >> 4;
  int cq = tid & 15;
#pragma unroll
  for (int q = 0; q < 4; ++q) {
    int r = q * 16 + rq;
    float4 v = *(const float4*)(src + (size_t)(tr + r) * C + tc + cq * 4);
    us4 b;
    b.x = f2bf(v.x); b.y = f2bf(v.y); b.z = f2bf(v.z); b.w = f2bf(v.w);
    *(us4*)&tile[r][cq * 4] = b;
  }
  __syncthreads();
#pragma unroll
  for (int q = 0; q < 4; ++q) {
    int cc = q * 16 + rq;
    int rr = cq * 4;
    us4 o;
    o.x = tile[rr + 0][cc]; o.y = tile[rr + 1][cc];
    o.z = tile[rr + 2][cc]; o.w = tile[rr + 3][cc];
    *(us4*)(dst + (size_t)(tc + cc) * R + tr + rr) = o;
  }
}

// ---------------- router (fp32) + fused x -> bf16 cast ----------------
__global__ void k_router(const float* __restrict__ x, const float* __restrict__ Wr,
                         const float* __restrict__ br, int* __restrict__ expert_id,
                         int* __restrict__ counts, unsigned short* __restrict__ xbf) {
  int token = blockIdx.x * 4 + (threadIdx.x >> 6);
  int lane  = threadIdx.x & 63;
  const float* xr = x + (size_t)token * D_IN;
  float acc[N_EXP];
#pragma unroll
  for (int e = 0; e < N_EXP; ++e) acc[e] = 0.f;
#pragma unroll
  for (int j = 0; j < 2; ++j) {
    int i0 = lane * 8 + j * 4;
    float4 xv = *(const float4*)(xr + i0);
    us4 bb;
    bb.x = f2bf(xv.x); bb.y = f2bf(xv.y); bb.z = f2bf(xv.z); bb.w = f2bf(xv.w);
    *(us4*)(xbf + (size_t)token * D_IN + i0) = bb;
    float xs[4] = {xv.x, xv.y, xv.z, xv.w};
#pragma unroll
    for (int u = 0; u < 4; ++u) {
      const float4* wr = (const float4*)(Wr + (size_t)(i0 + u) * N_EXP);
      float4 w0 = wr[0], w1 = wr[1];
      acc[0] += xs[u] * w0.x; acc[1] += xs[u] * w0.y;
      acc[2] += xs[u] * w0.z; acc[3] += xs[u] * w0.w;
      acc[4] += xs[u] * w1.x; acc[5] += xs[u] * w1.y;
      acc[6] += xs[u] * w1.z; acc[7] += xs[u] * w1.w;
    }
  }
#pragma unroll
  for (int off = 32; off > 0; off >>= 1) {
#pragma unroll
    for (int e = 0; e < N_EXP; ++e) acc[e] += __shfl_xor(acc[e], off, 64);
  }
  if (lane == 0) {
    float best = acc[0] + br[0]; int bi = 0;
#pragma unroll
    for (int e = 1; e < N_EXP; ++e) {
      float v = acc[e] + br[e];
      if (v > best) { best = v; bi = e; }   // first max wins (matches top_k)
    }
    expert_id[token] = bi;
    atomicAdd(&counts[bi], 1);
  }
}

// ---------------- parallel scan: offsets + cursors + expert-major tile table ----------------
__global__ void k_scan(const int* __restrict__ counts, int* __restrict__ offsets,
                       int* __restrict__ cursor, int2* __restrict__ table) {
  int i = threadIdx.x;   // 256 threads
  int s = 0, ts = 0, myexp = -1, myt = -1;
#pragma unroll
  for (int e = 0; e < N_EXP; ++e) {
    int c = counts[e];
    int tc = (c + BM - 1) / BM;
    if (i == e) { offsets[e] = s; cursor[e] = s; }
    if (i >= ts && i < ts + tc) { myexp = e; myt = i - ts; }
    s += c; ts += tc;
  }
  if (i < MAX_TILES) table[i] = make_int2(myexp, myt);
}

// ---------------- scatter: LDS histogram, one block-atomic per expert ----------------
__global__ void k_scatter(const int* __restrict__ expert_id, int* __restrict__ cursor,
                          int* __restrict__ idx_list) {
  __shared__ int lcnt[N_EXP], lbase[N_EXP];
  int tid = threadIdx.x;
  int i = blockIdx.x * 512 + tid;
  if (tid < N_EXP) lcnt[tid] = 0;
  __syncthreads();
  int e = expert_id[i];
  int lpos = atomicAdd(&lcnt[e], 1);
  __syncthreads();
  if (tid < N_EXP) lbase[tid] = atomicAdd(&cursor[tid], lcnt[tid]);
  __syncthreads();
  idx_list[lbase[e] + lpos] = i;
}

// ---------------- GEMM1: Hperm[perm_row, n] = relu(Xg @ W1T^T + b1), one H-chunk ----------------
// 256x256 tile, BK=64, 8 waves (2x4), dbuf LDS, global_load_lds staging (gathered A).
__launch_bounds__(512, 2)
__global__ void k_gemm1(const unsigned short* __restrict__ xbf,
                        const unsigned short* __restrict__ W1T,   // (E, H, D) bf16
                        const float* __restrict__ b1,
                        const int* __restrict__ counts, const int* __restrict__ offsets,
                        const int2* __restrict__ table, const int* __restrict__ idx_list,
                        unsigned short* __restrict__ Hperm,       // (N_TOK, hchunk) bf16
                        int nt1, int ch, int hchunk) {
  int ntile = blockIdx.x % nt1;           // consecutive bids share A-tile; ntile ~ XCD
  int tile  = blockIdx.x / nt1;
  int2 et = table[tile];
  int e = et.x;
  if (e < 0) return;
  int base   = offsets[e] + et.y * BM;
  int mvalid = min(BM, counts[e] - et.y * BM);

  __shared__ __align__(16) unsigned char lds[4][32 * 1024];  // A0,A1,B0,B1 (128 KB)

  int tid = threadIdx.x, w = tid >> 6, lane = tid & 63;
  int l15 = lane & 15, l4 = lane >> 4;
  int wr = w >> 2, wc = w & 3;
  int n0 = ch * hchunk + ntile * BN;      // global H-col base of this block

  unsigned offA[4], offB[4];
#pragma unroll
  for (int q = 0; q < 4; ++q) {
    int d   = (w * 4 + q) * 1024 + lane * 16;   // linear dest byte in 32KB tile
    int row = d >> 7;
    int bs  = (d & 127) ^ ((row & 7) << 4);     // inverse-swizzled byte-in-window
    int tok = idx_list[base + min(row, mvalid - 1)];
    offA[q] = (unsigned)tok * (D_IN * 2) + bs;
    offB[q] = (unsigned)(e * H_DIM + n0 + row) * (D_IN * 2) + bs;
  }

  f32x4 acc[8][4];
#pragma unroll
  for (int a = 0; a < 8; ++a)
#pragma unroll
    for (int b = 0; b < 4; ++b) acc[a][b] = (f32x4){0.f, 0.f, 0.f, 0.f};

#define STAGE1(buf, kstep) do {                                              \
    unsigned kb = (unsigned)(kstep) * 128u;                                  \
    _Pragma("unroll")                                                        \
    for (int q = 0; q < 4; ++q) {                                            \
      gll16((const char*)xbf + offA[q] + kb, &lds[(buf)][(w * 4 + q) * 1024]);      \
      gll16((const char*)W1T + offB[q] + kb, &lds[2 + (buf)][(w * 4 + q) * 1024]);  \
    }                                                                        \
  } while (0)

#define COMPUTE1(buf) do {                                                   \
    const unsigned char* A = lds[(buf)];                                     \
    const unsigned char* B = lds[2 + (buf)];                                 \
    _Pragma("unroll")                                                        \
    for (int ks = 0; ks < 2; ++ks) {                                         \
      int kb = ks * 64 + l4 * 16;                                            \
      bf16x8 bfr[4];                                                         \
      _Pragma("unroll")                                                      \
      for (int cf = 0; cf < 4; ++cf) {                                       \
        int n = wc * 64 + cf * 16 + l15;                                     \
        bfr[cf] = *(const bf16x8*)(B + n * 128 + (kb ^ ((n & 7) << 4)));     \
      }                                                                      \
      _Pragma("unroll")                                                      \
      for (int rf = 0; rf < 8; ++rf) {                                       \
        int m = wr * 128 + rf * 16 + l15;                                    \
        bf16x8 af = *(const bf16x8*)(A + m * 128 + (kb ^ ((m & 7) << 4)));   \
        _Pragma("unroll")                                                    \
        for (int cf = 0; cf < 4; ++cf)                                       \
          acc[rf][cf] = __builtin_amdgcn_mfma_f32_16x16x32_bf16(af, bfr[cf], acc[rf][cf], 0, 0, 0); \
      }                                                                      \
    }                                                                        \
  } while (0)

  const int NK = D_IN / BK;  // 8
  int cur = 0;
  STAGE1(0, 0);
  __syncthreads();
  for (int k = 0; k < NK - 1; ++k) {
    STAGE1(cur ^ 1, k + 1);
    COMPUTE1(cur);
    __syncthreads();
    cur ^= 1;
  }
  COMPUTE1(cur);

  // epilogue: bias + relu -> bf16 Hperm (permuted row order, chunk-local cols)
#pragma unroll
  for (int cf = 0; cf < 4; ++cf) {
    int ncol = ntile * BN + wc * 64 + cf * 16 + l15;     // within chunk
    float bv = b1[(size_t)e * H_DIM + ch * hchunk + ncol];
#pragma unroll
    for (int rf = 0; rf < 8; ++rf) {
#pragma unroll
      for (int j = 0; j < 4; ++j) {
        int row = wr * 128 + rf * 16 + l4 * 4 + j;
        if (row < mvalid) {
          float v = fmaxf(acc[rf][cf][j] + bv, 0.f);
          Hperm[(size_t)(base + row) * hchunk + ncol] = f2bf(v);
        }
      }
    }
  }
#undef STAGE1
#undef COMPUTE1
}

// ---------------- GEMM2: out[tok, o] (+)= Hperm @ W2T^T (+ b2), one H-chunk of K ----------------
__launch_bounds__(512, 2)
__global__ void k_gemm2(const unsigned short* __restrict__ Hperm,  // (N_TOK, hchunk) bf16
                        const unsigned short* __restrict__ W2T,    // (E, O, H) bf16
                        const float* __restrict__ b2,
                        const int* __restrict__ counts, const int* __restrict__ offsets,
                        const int2* __restrict__ table, const int* __restrict__ idx_list,
                        float* __restrict__ out,
                        int ch, int hchunk, int accumulate) {
  int ntile = blockIdx.x & 1;
  int tile  = blockIdx.x >> 1;
  int2 et = table[tile];
  int e = et.x;
  if (e < 0) return;
  int base   = offsets[e] + et.y * BM;
  int mvalid = min(BM, counts[e] - et.y * BM);

  __shared__ __align__(16) unsigned char lds[4][32 * 1024];

  int tid = threadIdx.x, w = tid >> 6, lane = tid & 63;
  int l15 = lane & 15, l4 = lane >> 4;
  int wr = w >> 2, wc = w & 3;
  int o0 = ntile * BN;
  const unsigned hrow_bytes = (unsigned)hchunk * 2;

  unsigned offA[4], offB[4];
#pragma unroll
  for (int q = 0; q < 4; ++q) {
    int d   = (w * 4 + q) * 1024 + lane * 16;
    int row = d >> 7;
    int bs  = (d & 127) ^ ((row & 7) << 4);
    offA[q] = (unsigned)min(base + row, N_TOK - 1) * hrow_bytes + bs;
    offB[q] = (unsigned)(e * O_DIM + o0 + row) * (H_DIM * 2) + (unsigned)ch * hchunk * 2 + bs;
  }

  f32x4 acc[8][4];
#pragma unroll
  for (int a = 0; a < 8; ++a)
#pragma unroll
    for (int b = 0; b < 4; ++b) acc[a][b] = (f32x4){0.f, 0.f, 0.f, 0.f};

#define STAGE2(buf, kstep) do {                                              \
    unsigned kb = (unsigned)(kstep) * 128u;                                  \
    _Pragma("unroll")                                                        \
    for (int q = 0; q < 4; ++q) {                                            \
      gll16((const char*)Hperm + offA[q] + kb, &lds[(buf)][(w * 4 + q) * 1024]);     \
      gll16((const char*)W2T   + offB[q] + kb, &lds[2 + (buf)][(w * 4 + q) * 1024]); \
    }                                                                        \
  } while (0)

#define COMPUTE2(buf) do {                                                   \
    const unsigned char* A = lds[(buf)];                                     \
    const unsigned char* B = lds[2 + (buf)];                                 \
    _Pragma("unroll")                                                        \
    for (int ks = 0; ks < 2; ++ks) {                                         \
      int kb = ks * 64 + l4 * 16;                                            \
      bf16x8 bfr[4];                                                         \
      _Pragma("unroll")                                                      \
      for (int cf = 0; cf < 4; ++cf) {                                       \
        int n = wc * 64 + cf * 16 + l15;                                     \
        bfr[cf] = *(const bf16x8*)(B + n * 128 + (kb ^ ((n & 7) << 4)));     \
      }                                                                      \
      _Pragma("unroll")                                                      \
      for (int rf = 0; rf < 8; ++rf) {                                       \
        int m = wr * 128 + rf * 16 + l15;                                    \
        bf16x8 af = *(const bf16x8*)(A + m * 128 + (kb ^ ((m & 7) << 4)));   \
        _Pragma("unroll")                                                    \
        for (int cf = 0; cf < 4; ++cf)                                       \
          acc[rf][cf] = __builtin_amdgcn_mfma_f32_16x16x32_bf16(af, bfr[cf], acc[rf][cf], 0, 0, 0); \
      }                                                                      \
    }                                                                        \
  } while (0)

  const int NK = hchunk / BK;
  int cur = 0;
  STAGE2(0, 0);
  __syncthreads();
  for (int k = 0; k < NK - 1; ++k) {
    STAGE2(cur ^ 1, k + 1);
    COMPUTE2(cur);
    __syncthreads();
    cur ^= 1;
  }
  COMPUTE2(cur);

  // epilogue: scatter to out (fp32), bias on first chunk, += afterwards
#pragma unroll
  for (int cf = 0; cf < 4; ++cf) {
    int o = o0 + wc * 64 + cf * 16 + l15;
    float bv = b2[(size_t)e * O_DIM + o];
#pragma unroll
    for (int rf = 0; rf < 8; ++rf) {
#pragma unroll
      for (int j = 0; j < 4; ++j) {
        int row = wr * 128 + rf * 16 + l4 * 4 + j;
        if (row < mvalid) {
          int tok = idx_list[base + row];
          float* p = out + (size_t)tok * O_DIM + o;
          if (accumulate) *p = *p + acc[rf][cf][j];
          else            *p = acc[rf][cf][j] + bv;
        }
      }
    }
  }
#undef STAGE2
#undef COMPUTE2
}

// ---------------- launch ----------------
extern "C" void kernel_launch(void* const* d_in, const int* in_sizes, int n_in,
                              void* d_out, int out_size, void* d_ws, size_t ws_size,
                              hipStream_t stream) {
  const float* x  = (const float*)d_in[0];
  const float* Wr = (const float*)d_in[1];
  const float* br = (const float*)d_in[2];
  const float* W1 = (const float*)d_in[3];
  const float* b1 = (const float*)d_in[4];
  const float* W2 = (const float*)d_in[5];
  const float* b2 = (const float*)d_in[6];
  float* out = (float*)d_out;

  char* ws = (char*)d_ws;
  int*  counts    = (int*)(ws + 0);
  int*  offsets   = (int*)(ws + 64);
  int*  cursor    = (int*)(ws + 128);
  int2* table     = (int2*)(ws + 256);                       // 144*8 B
  int*  expert_id = (int*)(ws + 2048);                       // 128 KB
  int*  idx_list  = (int*)(ws + 2048 + N_TOK * 4);           // 128 KB
  size_t off = 2048 + 2 * (size_t)N_TOK * 4;                 // 264192, 1KB-aligned
  unsigned short* xbf = (unsigned short*)(ws + off);         // 32 MB
  off += (size_t)N_TOK * D_IN * 2;
  unsigned short* W1T = (unsigned short*)(ws + off);         // 16 MB
  off += (size_t)N_EXP * H_DIM * D_IN * 2;
  unsigned short* W2T = (unsigned short*)(ws + off);         // 16 MB
  off += (size_t)N_EXP * H_DIM * O_DIM * 2;
  unsigned short* Hperm = (unsigned short*)(ws + off);

  // pick largest H-chunk that fits the remaining workspace (BN=256 floor)
  int hchunk = 2048;
  while (hchunk > 256 && off + (size_t)N_TOK * hchunk * 2 > ws_size) hchunk >>= 1;
  int nch = H_DIM / hchunk;
  int nt1 = hchunk / BN;

  k_init<<<1, 64, 0, stream>>>(counts);
  k_transpose<<<dim3(256, N_EXP), 256, 0, stream>>>(W1, W1T, D_IN, H_DIM);
  k_transpose<<<dim3(256, N_EXP), 256, 0, stream>>>(W2, W2T, H_DIM, O_DIM);
  k_router<<<N_TOK / 4, 256, 0, stream>>>(x, Wr, br, expert_id, counts, xbf);
  k_scan<<<1, 256, 0, stream>>>(counts, offsets, cursor, table);
  k_scatter<<<N_TOK / 512, 512, 0, stream>>>(expert_id, cursor, idx_list);

  for (int ch = 0; ch < nch; ++ch) {
    k_gemm1<<<MAX_TILES * nt1, 512, 0, stream>>>(xbf, W1T, b1, counts, offsets,
                                                 table, idx_list, Hperm, nt1, ch, hchunk);
    k_gemm2<<<MAX_TILES * 2, 512, 0, stream>>>(Hperm, W2T, b2, counts, offsets,
                                               table, idx_list, out, ch, hchunk, ch > 0);
  }
}

// Round 4
// 412.201 us; speedup vs baseline: 4.0496x; 1.7648x over previous
//
#include <hip/hip_runtime.h>
#include <stdint.h>

#define N_TOK 32768
#define D_IN  512
#define H_DIM 2048
#define O_DIM 512
#define N_EXP 8
#define BM    256
#define BN    256
#define BK    64
#define MAX_TILES 144   // 32768/256 = 128 full tiles + <=7 pad + slack

typedef __bf16 bf16x8 __attribute__((ext_vector_type(8)));
typedef float  f32x4  __attribute__((ext_vector_type(4)));

struct alignas(8) us4 { unsigned short x, y, z, w; };

__device__ __forceinline__ unsigned short f2bf(float f) {
  union { float f; unsigned u; } v; v.f = f;
  unsigned r = v.u + 0x7FFFu + ((v.u >> 16) & 1u);  // round-to-nearest-even
  return (unsigned short)(r >> 16);
}

// async global->LDS, 16B per lane; LDS dest must be wave-uniform base (+lane*16 by HW)
__device__ __forceinline__ void gll16(const void* src, void* lds_dst) {
  __builtin_amdgcn_global_load_lds(
      (const __attribute__((address_space(1))) void*)src,
      (__attribute__((address_space(3))) void*)lds_dst, 16, 0, 0);
}

// ---------------- init ----------------
__global__ void k_init(int* counts) {
  if (threadIdx.x < N_EXP) counts[threadIdx.x] = 0;
}

// ---------------- weight convert + transpose to bf16 ----------------
// W (E, R, C) fp32 row-major  ->  WT (E, C, R) bf16
__global__ void k_transpose(const float* __restrict__ W, unsigned short* __restrict__ WT,
                            int R, int C) {
  __shared__ unsigned short tile[64][72];
  int e = blockIdx.y;
  const float* src = W + (size_t)e * R * C;
  unsigned short* dst = WT + (size_t)e * R * C;
  int tilesC = C >> 6;
  int tc = (blockIdx.x % tilesC) << 6;
  int tr = (blockIdx.x / tilesC) << 6;
  int tid = threadIdx.x;
  int rq = tid >> 4;
  int cq = tid & 15;
#pragma unroll
  for (int q = 0; q < 4; ++q) {
    int r = q * 16 + rq;
    float4 v = *(const float4*)(src + (size_t)(tr + r) * C + tc + cq * 4);
    us4 b;
    b.x = f2bf(v.x); b.y = f2bf(v.y); b.z = f2bf(v.z); b.w = f2bf(v.w);
    *(us4*)&tile[r][cq * 4] = b;
  }
  __syncthreads();
#pragma unroll
  for (int q = 0; q < 4; ++q) {
    int cc = q * 16 + rq;
    int rr = cq * 4;
    us4 o;
    o.x = tile[rr + 0][cc]; o.y = tile[rr + 1][cc];
    o.z = tile[rr + 2][cc]; o.w = tile[rr + 3][cc];
    *(us4*)(dst + (size_t)(tc + cc) * R + tr + rr) = o;
  }
}

// ---------------- router (fp32) + fused x -> bf16 cast; NO atomics ----------------
__global__ void k_router(const float* __restrict__ x, const float* __restrict__ Wr,
                         const float* __restrict__ br, int* __restrict__ expert_id,
                         unsigned short* __restrict__ xbf) {
  int token = blockIdx.x * 4 + (threadIdx.x >> 6);
  int lane  = threadIdx.x & 63;
  const float* xr = x + (size_t)token * D_IN;
  float acc[N_EXP];
#pragma unroll
  for (int e = 0; e < N_EXP; ++e) acc[e] = 0.f;
#pragma unroll
  for (int j = 0; j < 2; ++j) {
    int i0 = lane * 8 + j * 4;
    float4 xv = *(const float4*)(xr + i0);
    us4 bb;
    bb.x = f2bf(xv.x); bb.y = f2bf(xv.y); bb.z = f2bf(xv.z); bb.w = f2bf(xv.w);
    *(us4*)(xbf + (size_t)token * D_IN + i0) = bb;
    float xs[4] = {xv.x, xv.y, xv.z, xv.w};
#pragma unroll
    for (int u = 0; u < 4; ++u) {
      const float4* wr = (const float4*)(Wr + (size_t)(i0 + u) * N_EXP);
      float4 w0 = wr[0], w1 = wr[1];
      acc[0] += xs[u] * w0.x; acc[1] += xs[u] * w0.y;
      acc[2] += xs[u] * w0.z; acc[3] += xs[u] * w0.w;
      acc[4] += xs[u] * w1.x; acc[5] += xs[u] * w1.y;
      acc[6] += xs[u] * w1.z; acc[7] += xs[u] * w1.w;
    }
  }
#pragma unroll
  for (int off = 32; off > 0; off >>= 1) {
#pragma unroll
    for (int e = 0; e < N_EXP; ++e) acc[e] += __shfl_xor(acc[e], off, 64);
  }
  if (lane == 0) {
    float best = acc[0] + br[0]; int bi = 0;
#pragma unroll
    for (int e = 1; e < N_EXP; ++e) {
      float v = acc[e] + br[e];
      if (v > best) { best = v; bi = e; }   // first max wins (matches top_k)
    }
    expert_id[token] = bi;
  }
}

// ---------------- count: LDS histogram, 8 global atomics per block ----------------
__global__ void k_count(const int* __restrict__ expert_id, int* __restrict__ counts) {
  __shared__ int lcnt[N_EXP];
  int tid = threadIdx.x;
  if (tid < N_EXP) lcnt[tid] = 0;
  __syncthreads();
  int e = expert_id[blockIdx.x * 1024 + tid];
  atomicAdd(&lcnt[e], 1);
  __syncthreads();
  if (tid < N_EXP) atomicAdd(&counts[tid], lcnt[tid]);
}

// ---------------- parallel scan: offsets + cursors + expert-major tile table ----------------
__global__ void k_scan(const int* __restrict__ counts, int* __restrict__ offsets,
                       int* __restrict__ cursor, int2* __restrict__ table) {
  int i = threadIdx.x;   // 256 threads
  int s = 0, ts = 0, myexp = -1, myt = -1;
#pragma unroll
  for (int e = 0; e < N_EXP; ++e) {
    int c = counts[e];
    int tc = (c + BM - 1) / BM;
    if (i == e) { offsets[e] = s; cursor[e] = s; }
    if (i >= ts && i < ts + tc) { myexp = e; myt = i - ts; }
    s += c; ts += tc;
  }
  if (i < MAX_TILES) table[i] = make_int2(myexp, myt);
}

// ---------------- scatter: LDS histogram, one block-atomic per expert ----------------
__global__ void k_scatter(const int* __restrict__ expert_id, int* __restrict__ cursor,
                          int* __restrict__ idx_list) {
  __shared__ int lcnt[N_EXP], lbase[N_EXP];
  int tid = threadIdx.x;
  int i = blockIdx.x * 512 + tid;
  if (tid < N_EXP) lcnt[tid] = 0;
  __syncthreads();
  int e = expert_id[i];
  int lpos = atomicAdd(&lcnt[e], 1);
  __syncthreads();
  if (tid < N_EXP) lbase[tid] = atomicAdd(&cursor[tid], lcnt[tid]);
  __syncthreads();
  idx_list[lbase[e] + lpos] = i;
}

// ---------------- GEMM1: Hperm[perm_row, n] = relu(Xg @ W1T^T + b1), one H-chunk ----------------
// 256x256 tile, BK=64, 8 waves (2x4), dbuf LDS, global_load_lds staging (gathered A).
__launch_bounds__(512, 2)
__global__ void k_gemm1(const unsigned short* __restrict__ xbf,
                        const unsigned short* __restrict__ W1T,   // (E, H, D) bf16
                        const float* __restrict__ b1,
                        const int* __restrict__ counts, const int* __restrict__ offsets,
                        const int2* __restrict__ table, const int* __restrict__ idx_list,
                        unsigned short* __restrict__ Hperm,       // (N_TOK, hchunk) bf16
                        int nt1, int ch, int hchunk) {
  int ntile = blockIdx.x % nt1;
  int tile  = blockIdx.x / nt1;
  int2 et = table[tile];
  int e = et.x;
  if (e < 0) return;
  int base   = offsets[e] + et.y * BM;
  int mvalid = min(BM, counts[e] - et.y * BM);

  __shared__ __align__(16) unsigned char lds[4][32 * 1024];  // A0,A1,B0,B1 (128 KB)

  int tid = threadIdx.x, w = tid >> 6, lane = tid & 63;
  int l15 = lane & 15, l4 = lane >> 4;
  int wr = w >> 2, wc = w & 3;
  int n0 = ch * hchunk + ntile * BN;

  unsigned offA[4], offB[4];
#pragma unroll
  for (int q = 0; q < 4; ++q) {
    int d   = (w * 4 + q) * 1024 + lane * 16;
    int row = d >> 7;
    int bs  = (d & 127) ^ ((row & 7) << 4);
    int tok = idx_list[base + min(row, mvalid - 1)];
    offA[q] = (unsigned)tok * (D_IN * 2) + bs;
    offB[q] = (unsigned)(e * H_DIM + n0 + row) * (D_IN * 2) + bs;
  }

  f32x4 acc[8][4];
#pragma unroll
  for (int a = 0; a < 8; ++a)
#pragma unroll
    for (int b = 0; b < 4; ++b) acc[a][b] = (f32x4){0.f, 0.f, 0.f, 0.f};

#define STAGE1(buf, kstep) do {                                              \
    unsigned kb = (unsigned)(kstep) * 128u;                                  \
    _Pragma("unroll")                                                        \
    for (int q = 0; q < 4; ++q) {                                            \
      gll16((const char*)xbf + offA[q] + kb, &lds[(buf)][(w * 4 + q) * 1024]);      \
      gll16((const char*)W1T + offB[q] + kb, &lds[2 + (buf)][(w * 4 + q) * 1024]);  \
    }                                                                        \
  } while (0)

#define COMPUTE1(buf) do {                                                   \
    const unsigned char* A = lds[(buf)];                                     \
    const unsigned char* B = lds[2 + (buf)];                                 \
    _Pragma("unroll")                                                        \
    for (int ks = 0; ks < 2; ++ks) {                                         \
      int kb = ks * 64 + l4 * 16;                                            \
      bf16x8 bfr[4];                                                         \
      _Pragma("unroll")                                                      \
      for (int cf = 0; cf < 4; ++cf) {                                       \
        int n = wc * 64 + cf * 16 + l15;                                     \
        bfr[cf] = *(const bf16x8*)(B + n * 128 + (kb ^ ((n & 7) << 4)));     \
      }                                                                      \
      _Pragma("unroll")                                                      \
      for (int rf = 0; rf < 8; ++rf) {                                       \
        int m = wr * 128 + rf * 16 + l15;                                    \
        bf16x8 af = *(const bf16x8*)(A + m * 128 + (kb ^ ((m & 7) << 4)));   \
        _Pragma("unroll")                                                    \
        for (int cf = 0; cf < 4; ++cf)                                       \
          acc[rf][cf] = __builtin_amdgcn_mfma_f32_16x16x32_bf16(af, bfr[cf], acc[rf][cf], 0, 0, 0); \
      }                                                                      \
    }                                                                        \
  } while (0)

  const int NK = D_IN / BK;  // 8
  int cur = 0;
  STAGE1(0, 0);
  __syncthreads();
  for (int k = 0; k < NK - 1; ++k) {
    STAGE1(cur ^ 1, k + 1);
    COMPUTE1(cur);
    __syncthreads();
    cur ^= 1;
  }
  COMPUTE1(cur);

  // epilogue: bias + relu -> bf16 Hperm (permuted row order, chunk-local cols)
#pragma unroll
  for (int cf = 0; cf < 4; ++cf) {
    int ncol = ntile * BN + wc * 64 + cf * 16 + l15;
    float bv = b1[(size_t)e * H_DIM + ch * hchunk + ncol];
#pragma unroll
    for (int rf = 0; rf < 8; ++rf) {
#pragma unroll
      for (int j = 0; j < 4; ++j) {
        int row = wr * 128 + rf * 16 + l4 * 4 + j;
        if (row < mvalid) {
          float v = fmaxf(acc[rf][cf][j] + bv, 0.f);
          Hperm[(size_t)(base + row) * hchunk + ncol] = f2bf(v);
        }
      }
    }
  }
#undef STAGE1
#undef COMPUTE1
}

// ---------------- GEMM2: out[tok, o] (+)= Hperm @ W2T^T (+ b2), one H-chunk of K ----------------
__launch_bounds__(512, 2)
__global__ void k_gemm2(const unsigned short* __restrict__ Hperm,  // (N_TOK, hchunk) bf16
                        const unsigned short* __restrict__ W2T,    // (E, O, H) bf16
                        const float* __restrict__ b2,
                        const int* __restrict__ counts, const int* __restrict__ offsets,
                        const int2* __restrict__ table, const int* __restrict__ idx_list,
                        float* __restrict__ out,
                        int ch, int hchunk, int accumulate) {
  int ntile = blockIdx.x & 1;
  int tile  = blockIdx.x >> 1;
  int2 et = table[tile];
  int e = et.x;
  if (e < 0) return;
  int base   = offsets[e] + et.y * BM;
  int mvalid = min(BM, counts[e] - et.y * BM);

  __shared__ __align__(16) unsigned char lds[4][32 * 1024];

  int tid = threadIdx.x, w = tid >> 6, lane = tid & 63;
  int l15 = lane & 15, l4 = lane >> 4;
  int wr = w >> 2, wc = w & 3;
  int o0 = ntile * BN;
  const unsigned hrow_bytes = (unsigned)hchunk * 2;

  unsigned offA[4], offB[4];
#pragma unroll
  for (int q = 0; q < 4; ++q) {
    int d   = (w * 4 + q) * 1024 + lane * 16;
    int row = d >> 7;
    int bs  = (d & 127) ^ ((row & 7) << 4);
    offA[q] = (unsigned)min(base + row, N_TOK - 1) * hrow_bytes + bs;
    offB[q] = (unsigned)(e * O_DIM + o0 + row) * (H_DIM * 2) + (unsigned)ch * hchunk * 2 + bs;
  }

  f32x4 acc[8][4];
#pragma unroll
  for (int a = 0; a < 8; ++a)
#pragma unroll
    for (int b = 0; b < 4; ++b) acc[a][b] = (f32x4){0.f, 0.f, 0.f, 0.f};

#define STAGE2(buf, kstep) do {                                              \
    unsigned kb = (unsigned)(kstep) * 128u;                                  \
    _Pragma("unroll")                                                        \
    for (int q = 0; q < 4; ++q) {                                            \
      gll16((const char*)Hperm + offA[q] + kb, &lds[(buf)][(w * 4 + q) * 1024]);     \
      gll16((const char*)W2T   + offB[q] + kb, &lds[2 + (buf)][(w * 4 + q) * 1024]); \
    }                                                                        \
  } while (0)

#define COMPUTE2(buf) do {                                                   \
    const unsigned char* A = lds[(buf)];                                     \
    const unsigned char* B = lds[2 + (buf)];                                 \
    _Pragma("unroll")                                                        \
    for (int ks = 0; ks < 2; ++ks) {                                         \
      int kb = ks * 64 + l4 * 16;                                            \
      bf16x8 bfr[4];                                                         \
      _Pragma("unroll")                                                      \
      for (int cf = 0; cf < 4; ++cf) {                                       \
        int n = wc * 64 + cf * 16 + l15;                                     \
        bfr[cf] = *(const bf16x8*)(B + n * 128 + (kb ^ ((n & 7) << 4)));     \
      }                                                                      \
      _Pragma("unroll")                                                      \
      for (int rf = 0; rf < 8; ++rf) {                                       \
        int m = wr * 128 + rf * 16 + l15;                                    \
        bf16x8 af = *(const bf16x8*)(A + m * 128 + (kb ^ ((m & 7) << 4)));   \
        _Pragma("unroll")                                                    \
        for (int cf = 0; cf < 4; ++cf)                                       \
          acc[rf][cf] = __builtin_amdgcn_mfma_f32_16x16x32_bf16(af, bfr[cf], acc[rf][cf], 0, 0, 0); \
      }                                                                      \
    }                                                                        \
  } while (0)

  const int NK = hchunk / BK;
  int cur = 0;
  STAGE2(0, 0);
  __syncthreads();
  for (int k = 0; k < NK - 1; ++k) {
    STAGE2(cur ^ 1, k + 1);
    COMPUTE2(cur);
    __syncthreads();
    cur ^= 1;
  }
  COMPUTE2(cur);

  // epilogue: scatter to out (fp32), bias on first chunk, += afterwards
#pragma unroll
  for (int cf = 0; cf < 4; ++cf) {
    int o = o0 + wc * 64 + cf * 16 + l15;
    float bv = b2[(size_t)e * O_DIM + o];
#pragma unroll
    for (int rf = 0; rf < 8; ++rf) {
#pragma unroll
      for (int j = 0; j < 4; ++j) {
        int row = wr * 128 + rf * 16 + l4 * 4 + j;
        if (row < mvalid) {
          int tok = idx_list[base + row];
          float* p = out + (size_t)tok * O_DIM + o;
          if (accumulate) *p = *p + acc[rf][cf][j];
          else            *p = acc[rf][cf][j] + bv;
        }
      }
    }
  }
#undef STAGE2
#undef COMPUTE2
}

// ---------------- launch ----------------
extern "C" void kernel_launch(void* const* d_in, const int* in_sizes, int n_in,
                              void* d_out, int out_size, void* d_ws, size_t ws_size,
                              hipStream_t stream) {
  const float* x  = (const float*)d_in[0];
  const float* Wr = (const float*)d_in[1];
  const float* br = (const float*)d_in[2];
  const float* W1 = (const float*)d_in[3];
  const float* b1 = (const float*)d_in[4];
  const float* W2 = (const float*)d_in[5];
  const float* b2 = (const float*)d_in[6];
  float* out = (float*)d_out;

  char* ws = (char*)d_ws;
  int*  counts    = (int*)(ws + 0);
  int*  offsets   = (int*)(ws + 64);
  int*  cursor    = (int*)(ws + 128);
  int2* table     = (int2*)(ws + 256);                       // 144*8 B
  int*  expert_id = (int*)(ws + 2048);                       // 128 KB
  int*  idx_list  = (int*)(ws + 2048 + N_TOK * 4);           // 128 KB
  size_t off = 2048 + 2 * (size_t)N_TOK * 4;                 // 1KB-aligned
  unsigned short* xbf = (unsigned short*)(ws + off);         // 32 MB
  off += (size_t)N_TOK * D_IN * 2;
  unsigned short* W1T = (unsigned short*)(ws + off);         // 16 MB
  off += (size_t)N_EXP * H_DIM * D_IN * 2;
  unsigned short* W2T = (unsigned short*)(ws + off);         // 16 MB
  off += (size_t)N_EXP * H_DIM * O_DIM * 2;
  unsigned short* Hperm = (unsigned short*)(ws + off);

  // pick largest H-chunk that fits the remaining workspace (BN=256 floor)
  int hchunk = 2048;
  while (hchunk > 256 && off + (size_t)N_TOK * hchunk * 2 > ws_size) hchunk >>= 1;
  int nch = H_DIM / hchunk;
  int nt1 = hchunk / BN;

  k_init<<<1, 64, 0, stream>>>(counts);
  k_transpose<<<dim3(256, N_EXP), 256, 0, stream>>>(W1, W1T, D_IN, H_DIM);
  k_transpose<<<dim3(256, N_EXP), 256, 0, stream>>>(W2, W2T, H_DIM, O_DIM);
  k_router<<<N_TOK / 4, 256, 0, stream>>>(x, Wr, br, expert_id, xbf);
  k_count<<<N_TOK / 1024, 1024, 0, stream>>>(expert_id, counts);
  k_scan<<<1, 256, 0, stream>>>(counts, offsets, cursor, table);
  k_scatter<<<N_TOK / 512, 512, 0, stream>>>(expert_id, cursor, idx_list);

  for (int ch = 0; ch < nch; ++ch) {
    k_gemm1<<<MAX_TILES * nt1, 512, 0, stream>>>(xbf, W1T, b1, counts, offsets,
                                                 table, idx_list, Hperm, nt1, ch, hchunk);
    k_gemm2<<<MAX_TILES * 2, 512, 0, stream>>>(Hperm, W2T, b2, counts, offsets,
                                               table, idx_list, out, ch, hchunk, ch > 0);
  }
}

// Round 5
// 397.936 us; speedup vs baseline: 4.1948x; 1.0358x over previous
//
#include <hip/hip_runtime.h>
#include <stdint.h>

#define N_TOK 32768
#define D_IN  512
#define H_DIM 2048
#define O_DIM 512
#define N_EXP 8
#define BM    256
#define BN    256
#define BK    64
#define MAX_TILES 144   // 32768/256 = 128 full tiles + <=7 pad + slack

typedef __bf16 bf16x8 __attribute__((ext_vector_type(8)));
typedef float  f32x4  __attribute__((ext_vector_type(4)));
typedef unsigned int u32x4 __attribute__((ext_vector_type(4)));

struct alignas(8) us4 { unsigned short x, y, z, w; };

#define FENCE() asm volatile("" ::: "memory")
#define BAR()   do { FENCE(); __builtin_amdgcn_s_barrier(); FENCE(); } while (0)
#define WAITV8  asm volatile("s_waitcnt vmcnt(8)" ::: "memory")
#define WAITV0  asm volatile("s_waitcnt vmcnt(0)" ::: "memory")

__device__ __forceinline__ unsigned short f2bf(float f) {
  union { float f; unsigned u; } v; v.f = f;
  unsigned r = v.u + 0x7FFFu + ((v.u >> 16) & 1u);  // round-to-nearest-even
  return (unsigned short)(r >> 16);
}

// async global->LDS, 16B per lane; LDS dest is wave-uniform base (+lane*16 by HW)
__device__ __forceinline__ void gll16(const void* src, void* lds_dst) {
  __builtin_amdgcn_global_load_lds(
      (const __attribute__((address_space(1))) void*)src,
      (__attribute__((address_space(3))) void*)lds_dst, 16, 0, 0);
}

// ---------------- init ----------------
__global__ void k_init(int* counts) {
  if (threadIdx.x < N_EXP) counts[threadIdx.x] = 0;
}

// ---------------- weight convert + transpose to bf16 ----------------
// W (E, R, C) fp32 row-major  ->  WT (E, C, R) bf16
__global__ void k_transpose(const float* __restrict__ W, unsigned short* __restrict__ WT,
                            int R, int C) {
  __shared__ unsigned short tile[64][72];
  int e = blockIdx.y;
  const float* src = W + (size_t)e * R * C;
  unsigned short* dst = WT + (size_t)e * R * C;
  int tilesC = C >> 6;
  int tc = (blockIdx.x % tilesC) << 6;
  int tr = (blockIdx.x / tilesC) << 6;
  int tid = threadIdx.x;
  int rq = tid >> 4;
  int cq = tid & 15;
#pragma unroll
  for (int q = 0; q < 4; ++q) {
    int r = q * 16 + rq;
    float4 v = *(const float4*)(src + (size_t)(tr + r) * C + tc + cq * 4);
    us4 b;
    b.x = f2bf(v.x); b.y = f2bf(v.y); b.z = f2bf(v.z); b.w = f2bf(v.w);
    *(us4*)&tile[r][cq * 4] = b;
  }
  __syncthreads();
#pragma unroll
  for (int q = 0; q < 4; ++q) {
    int cc = q * 16 + rq;
    int rr = cq * 4;
    us4 o;
    o.x = tile[rr + 0][cc]; o.y = tile[rr + 1][cc];
    o.z = tile[rr + 2][cc]; o.w = tile[rr + 3][cc];
    *(us4*)(dst + (size_t)(tc + cc) * R + tr + rr) = o;
  }
}

// ---------------- router (fp32) + fused x -> bf16 cast; NO atomics ----------------
__global__ void k_router(const float* __restrict__ x, const float* __restrict__ Wr,
                         const float* __restrict__ br, int* __restrict__ expert_id,
                         unsigned short* __restrict__ xbf) {
  int token = blockIdx.x * 4 + (threadIdx.x >> 6);
  int lane  = threadIdx.x & 63;
  const float* xr = x + (size_t)token * D_IN;
  float acc[N_EXP];
#pragma unroll
  for (int e = 0; e < N_EXP; ++e) acc[e] = 0.f;
#pragma unroll
  for (int j = 0; j < 2; ++j) {
    int i0 = lane * 8 + j * 4;
    float4 xv = *(const float4*)(xr + i0);
    us4 bb;
    bb.x = f2bf(xv.x); bb.y = f2bf(xv.y); bb.z = f2bf(xv.z); bb.w = f2bf(xv.w);
    *(us4*)(xbf + (size_t)token * D_IN + i0) = bb;
    float xs[4] = {xv.x, xv.y, xv.z, xv.w};
#pragma unroll
    for (int u = 0; u < 4; ++u) {
      const float4* wr = (const float4*)(Wr + (size_t)(i0 + u) * N_EXP);
      float4 w0 = wr[0], w1 = wr[1];
      acc[0] += xs[u] * w0.x; acc[1] += xs[u] * w0.y;
      acc[2] += xs[u] * w0.z; acc[3] += xs[u] * w0.w;
      acc[4] += xs[u] * w1.x; acc[5] += xs[u] * w1.y;
      acc[6] += xs[u] * w1.z; acc[7] += xs[u] * w1.w;
    }
  }
#pragma unroll
  for (int off = 32; off > 0; off >>= 1) {
#pragma unroll
    for (int e = 0; e < N_EXP; ++e) acc[e] += __shfl_xor(acc[e], off, 64);
  }
  if (lane == 0) {
    float best = acc[0] + br[0]; int bi = 0;
#pragma unroll
    for (int e = 1; e < N_EXP; ++e) {
      float v = acc[e] + br[e];
      if (v > best) { best = v; bi = e; }   // first max wins (matches top_k)
    }
    expert_id[token] = bi;
  }
}

// ---------------- count: LDS histogram, 8 global atomics per block ----------------
__global__ void k_count(const int* __restrict__ expert_id, int* __restrict__ counts) {
  __shared__ int lcnt[N_EXP];
  int tid = threadIdx.x;
  if (tid < N_EXP) lcnt[tid] = 0;
  __syncthreads();
  int e = expert_id[blockIdx.x * 1024 + tid];
  atomicAdd(&lcnt[e], 1);
  __syncthreads();
  if (tid < N_EXP) atomicAdd(&counts[tid], lcnt[tid]);
}

// ---------------- parallel scan: offsets + cursors + expert-major tile table ----------------
__global__ void k_scan(const int* __restrict__ counts, int* __restrict__ offsets,
                       int* __restrict__ cursor, int2* __restrict__ table) {
  int i = threadIdx.x;   // 256 threads
  int s = 0, ts = 0, myexp = -1, myt = -1;
#pragma unroll
  for (int e = 0; e < N_EXP; ++e) {
    int c = counts[e];
    int tc = (c + BM - 1) / BM;
    if (i == e) { offsets[e] = s; cursor[e] = s; }
    if (i >= ts && i < ts + tc) { myexp = e; myt = i - ts; }
    s += c; ts += tc;
  }
  if (i < MAX_TILES) table[i] = make_int2(myexp, myt);
}

// ---------------- scatter: LDS histogram, one block-atomic per expert ----------------
__global__ void k_scatter(const int* __restrict__ expert_id, int* __restrict__ cursor,
                          int* __restrict__ idx_list) {
  __shared__ int lcnt[N_EXP], lbase[N_EXP];
  int tid = threadIdx.x;
  int i = blockIdx.x * 512 + tid;
  if (tid < N_EXP) lcnt[tid] = 0;
  __syncthreads();
  int e = expert_id[i];
  int lpos = atomicAdd(&lcnt[e], 1);
  __syncthreads();
  if (tid < N_EXP) lbase[tid] = atomicAdd(&cursor[tid], lcnt[tid]);
  __syncthreads();
  idx_list[lbase[e] + lpos] = i;
}

// ---------------- GEMM1: Hperm[perm_row, n] = relu(Xg @ W1T^T + b1) ----------------
// 256x256 tile, BK=64, 8 waves (2x4), 2-deep counted-vmcnt pipeline, LDS-bounce epilogue.
__launch_bounds__(512, 2)
__global__ void k_gemm1(const unsigned short* __restrict__ xbf,
                        const unsigned short* __restrict__ W1T,   // (E, H, D) bf16
                        const float* __restrict__ b1,
                        const int* __restrict__ counts, const int* __restrict__ offsets,
                        const int2* __restrict__ table, const int* __restrict__ idx_list,
                        unsigned short* __restrict__ Hperm,       // (N_TOK, hchunk) bf16
                        int nt1, int ch, int hchunk) {
  int ntile = blockIdx.x % nt1;
  int tile  = blockIdx.x / nt1;
  int2 et = table[tile];
  int e = et.x;
  if (e < 0) return;
  int base   = offsets[e] + et.y * BM;
  int mvalid = min(BM, counts[e] - et.y * BM);

  __shared__ __align__(16) unsigned char lds_raw[131072];  // A0,A1,B0,B1 / C-tile bounce

  int tid = threadIdx.x, w = tid >> 6, lane = tid & 63;
  int l15 = lane & 15, l4 = lane >> 4;
  int wr = w >> 2, wc = w & 3;
  int n0 = ch * hchunk + ntile * BN;

  unsigned offA[4], offB[4];
#pragma unroll
  for (int q = 0; q < 4; ++q) {
    int d   = (w * 4 + q) * 1024 + lane * 16;
    int row = d >> 7;
    int bs  = (d & 127) ^ ((row & 7) << 4);
    int tok = idx_list[base + min(row, mvalid - 1)];
    offA[q] = (unsigned)tok * (D_IN * 2) + bs;
    offB[q] = (unsigned)(e * H_DIM + n0 + row) * (D_IN * 2) + bs;
  }

  f32x4 acc[8][4];
#pragma unroll
  for (int a = 0; a < 8; ++a)
#pragma unroll
    for (int b = 0; b < 4; ++b) acc[a][b] = (f32x4){0.f, 0.f, 0.f, 0.f};

#define STAGE1(buf, kstep) do {                                              \
    unsigned kb = (unsigned)(kstep) * 128u;                                  \
    unsigned char* da = lds_raw + (unsigned)(buf) * 32768u;                  \
    unsigned char* db = lds_raw + 65536u + (unsigned)(buf) * 32768u;         \
    _Pragma("unroll")                                                        \
    for (int q = 0; q < 4; ++q) {                                            \
      gll16((const char*)xbf + offA[q] + kb, da + (w * 4 + q) * 1024);       \
      gll16((const char*)W1T + offB[q] + kb, db + (w * 4 + q) * 1024);       \
    }                                                                        \
  } while (0)

#define COMPUTE1(buf) do {                                                   \
    const unsigned char* A = lds_raw + (unsigned)(buf) * 32768u;             \
    const unsigned char* B = lds_raw + 65536u + (unsigned)(buf) * 32768u;    \
    __builtin_amdgcn_s_setprio(1);                                           \
    _Pragma("unroll")                                                        \
    for (int ks = 0; ks < 2; ++ks) {                                         \
      int kb = ks * 64 + l4 * 16;                                            \
      bf16x8 bfr[4];                                                         \
      _Pragma("unroll")                                                      \
      for (int cf = 0; cf < 4; ++cf) {                                       \
        int n = wc * 64 + cf * 16 + l15;                                     \
        bfr[cf] = *(const bf16x8*)(B + n * 128 + (kb ^ ((n & 7) << 4)));     \
      }                                                                      \
      _Pragma("unroll")                                                      \
      for (int rf = 0; rf < 8; ++rf) {                                       \
        int m = wr * 128 + rf * 16 + l15;                                    \
        bf16x8 af = *(const bf16x8*)(A + m * 128 + (kb ^ ((m & 7) << 4)));   \
        _Pragma("unroll")                                                    \
        for (int cf = 0; cf < 4; ++cf)                                       \
          acc[rf][cf] = __builtin_amdgcn_mfma_f32_16x16x32_bf16(af, bfr[cf], acc[rf][cf], 0, 0, 0); \
      }                                                                      \
    }                                                                        \
    __builtin_amdgcn_s_setprio(0);                                           \
  } while (0)

  const int NK = D_IN / BK;  // 8
  STAGE1(0, 0);
  STAGE1(1, 1);
  WAITV8;                 // buf0 landed (buf1's 8 still in flight)
  BAR();
  for (int k = 0; k < NK - 1; ++k) {
    COMPUTE1(k & 1);
    BAR();                               // all waves done reading buf[k&1]
    if (k + 2 < NK) { STAGE1(k & 1, k + 2); WAITV8; }   // wait k+1, keep k+2 in flight
    else            { WAITV0; }                          // drain last tile
    BAR();                               // staged data visible to all waves
  }
  COMPUTE1((NK - 1) & 1);
  BAR();                                 // staging reads done; LDS reusable

  // ---- epilogue: bias+relu -> LDS C-tile (bf16, stride 512B, XOR swz) -> coalesced stores ----
#pragma unroll
  for (int cf = 0; cf < 4; ++cf) {
    int ncol = ntile * BN + wc * 64 + cf * 16 + l15;
    float bv = b1[(size_t)e * H_DIM + ch * hchunk + ncol];
#pragma unroll
    for (int rf = 0; rf < 8; ++rf) {
#pragma unroll
      for (int j = 0; j < 4; ++j) {
        int row = wr * 128 + rf * 16 + l4 * 4 + j;
        int cb  = ((wc * 64 + cf * 16 + l15) * 2) ^ ((row & 7) << 4);
        float v = fmaxf(acc[rf][cf][j] + bv, 0.f);
        *(unsigned short*)(lds_raw + row * 512 + cb) = f2bf(v);
      }
    }
  }
  BAR();
  {
    int row = tid >> 1;
    if (row < mvalid) {
      int hb = (tid & 1) * 256;
      int swz = (row & 7) << 4;
      char* gdst = (char*)Hperm + ((size_t)(base + row) * hchunk + ntile * BN) * 2 + hb;
      const unsigned char* lsrc = lds_raw + row * 512;
#pragma unroll
      for (int i = 0; i < 16; ++i) {
        u32x4 v = *(const u32x4*)(lsrc + ((hb + i * 16) ^ swz));
        *(u32x4*)(gdst + i * 16) = v;
      }
    }
  }
#undef STAGE1
#undef COMPUTE1
}

// ---------------- GEMM2: out[tok, o] (+)= Hperm @ W2T^T (+ b2) ----------------
__launch_bounds__(512, 2)
__global__ void k_gemm2(const unsigned short* __restrict__ Hperm,  // (N_TOK, hchunk) bf16
                        const unsigned short* __restrict__ W2T,    // (E, O, H) bf16
                        const float* __restrict__ b2,
                        const int* __restrict__ counts, const int* __restrict__ offsets,
                        const int2* __restrict__ table, const int* __restrict__ idx_list,
                        float* __restrict__ out,
                        int ch, int hchunk, int accumulate) {
  int ntile = blockIdx.x & 1;
  int tile  = blockIdx.x >> 1;
  int2 et = table[tile];
  int e = et.x;
  if (e < 0) return;
  int base   = offsets[e] + et.y * BM;
  int mvalid = min(BM, counts[e] - et.y * BM);

  __shared__ __align__(16) unsigned char lds_raw[131072];

  int tid = threadIdx.x, w = tid >> 6, lane = tid & 63;
  int l15 = lane & 15, l4 = lane >> 4;
  int wr = w >> 2, wc = w & 3;
  int o0 = ntile * BN;
  const unsigned hrow_bytes = (unsigned)hchunk * 2;

  unsigned offA[4], offB[4];
#pragma unroll
  for (int q = 0; q < 4; ++q) {
    int d   = (w * 4 + q) * 1024 + lane * 16;
    int row = d >> 7;
    int bs  = (d & 127) ^ ((row & 7) << 4);
    offA[q] = (unsigned)min(base + row, N_TOK - 1) * hrow_bytes + bs;
    offB[q] = (unsigned)(e * O_DIM + o0 + row) * (H_DIM * 2) + (unsigned)ch * hchunk * 2 + bs;
  }

  f32x4 acc[8][4];
#pragma unroll
  for (int a = 0; a < 8; ++a)
#pragma unroll
    for (int b = 0; b < 4; ++b) acc[a][b] = (f32x4){0.f, 0.f, 0.f, 0.f};

#define STAGE2(buf, kstep) do {                                              \
    unsigned kb = (unsigned)(kstep) * 128u;                                  \
    unsigned char* da = lds_raw + (unsigned)(buf) * 32768u;                  \
    unsigned char* db = lds_raw + 65536u + (unsigned)(buf) * 32768u;         \
    _Pragma("unroll")                                                        \
    for (int q = 0; q < 4; ++q) {                                            \
      gll16((const char*)Hperm + offA[q] + kb, da + (w * 4 + q) * 1024);     \
      gll16((const char*)W2T   + offB[q] + kb, db + (w * 4 + q) * 1024);     \
    }                                                                        \
  } while (0)

#define COMPUTE2(buf) do {                                                   \
    const unsigned char* A = lds_raw + (unsigned)(buf) * 32768u;             \
    const unsigned char* B = lds_raw + 65536u + (unsigned)(buf) * 32768u;    \
    __builtin_amdgcn_s_setprio(1);                                           \
    _Pragma("unroll")                                                        \
    for (int ks = 0; ks < 2; ++ks) {                                         \
      int kb = ks * 64 + l4 * 16;                                            \
      bf16x8 bfr[4];                                                         \
      _Pragma("unroll")                                                      \
      for (int cf = 0; cf < 4; ++cf) {                                       \
        int n = wc * 64 + cf * 16 + l15;                                     \
        bfr[cf] = *(const bf16x8*)(B + n * 128 + (kb ^ ((n & 7) << 4)));     \
      }                                                                      \
      _Pragma("unroll")                                                      \
      for (int rf = 0; rf < 8; ++rf) {                                       \
        int m = wr * 128 + rf * 16 + l15;                                    \
        bf16x8 af = *(const bf16x8*)(A + m * 128 + (kb ^ ((m & 7) << 4)));   \
        _Pragma("unroll")                                                    \
        for (int cf = 0; cf < 4; ++cf)                                       \
          acc[rf][cf] = __builtin_amdgcn_mfma_f32_16x16x32_bf16(af, bfr[cf], acc[rf][cf], 0, 0, 0); \
      }                                                                      \
    }                                                                        \
    __builtin_amdgcn_s_setprio(0);                                           \
  } while (0)

  const int NK = hchunk / BK;
  STAGE2(0, 0);
  STAGE2(1, 1);
  WAITV8;
  BAR();
  for (int k = 0; k < NK - 1; ++k) {
    COMPUTE2(k & 1);
    BAR();
    if (k + 2 < NK) { STAGE2(k & 1, k + 2); WAITV8; }
    else            { WAITV0; }
    BAR();
  }
  COMPUTE2((NK - 1) & 1);

  // epilogue: scatter to out (fp32, 64B-contiguous per 16 lanes), bias on first chunk
#pragma unroll
  for (int cf = 0; cf < 4; ++cf) {
    int o = o0 + wc * 64 + cf * 16 + l15;
    float bv = b2[(size_t)e * O_DIM + o];
#pragma unroll
    for (int rf = 0; rf < 8; ++rf) {
#pragma unroll
      for (int j = 0; j < 4; ++j) {
        int row = wr * 128 + rf * 16 + l4 * 4 + j;
        if (row < mvalid) {
          int tok = idx_list[base + row];
          float* p = out + (size_t)tok * O_DIM + o;
          if (accumulate) *p = *p + acc[rf][cf][j];
          else            *p = acc[rf][cf][j] + bv;
        }
      }
    }
  }
#undef STAGE2
#undef COMPUTE2
}

// ---------------- launch ----------------
extern "C" void kernel_launch(void* const* d_in, const int* in_sizes, int n_in,
                              void* d_out, int out_size, void* d_ws, size_t ws_size,
                              hipStream_t stream) {
  const float* x  = (const float*)d_in[0];
  const float* Wr = (const float*)d_in[1];
  const float* br = (const float*)d_in[2];
  const float* W1 = (const float*)d_in[3];
  const float* b1 = (const float*)d_in[4];
  const float* W2 = (const float*)d_in[5];
  const float* b2 = (const float*)d_in[6];
  float* out = (float*)d_out;

  char* ws = (char*)d_ws;
  int*  counts    = (int*)(ws + 0);
  int*  offsets   = (int*)(ws + 64);
  int*  cursor    = (int*)(ws + 128);
  int2* table     = (int2*)(ws + 256);                       // 144*8 B
  int*  expert_id = (int*)(ws + 2048);                       // 128 KB
  int*  idx_list  = (int*)(ws + 2048 + N_TOK * 4);           // 128 KB
  size_t off = 2048 + 2 * (size_t)N_TOK * 4;                 // 1KB-aligned
  unsigned short* xbf = (unsigned short*)(ws + off);         // 32 MB
  off += (size_t)N_TOK * D_IN * 2;
  unsigned short* W1T = (unsigned short*)(ws + off);         // 16 MB
  off += (size_t)N_EXP * H_DIM * D_IN * 2;
  unsigned short* W2T = (unsigned short*)(ws + off);         // 16 MB
  off += (size_t)N_EXP * H_DIM * O_DIM * 2;
  unsigned short* Hperm = (unsigned short*)(ws + off);

  // pick largest H-chunk that fits the remaining workspace (BN=256 floor)
  int hchunk = 2048;
  while (hchunk > 256 && off + (size_t)N_TOK * hchunk * 2 > ws_size) hchunk >>= 1;
  int nch = H_DIM / hchunk;
  int nt1 = hchunk / BN;

  k_init<<<1, 64, 0, stream>>>(counts);
  k_transpose<<<dim3(256, N_EXP), 256, 0, stream>>>(W1, W1T, D_IN, H_DIM);
  k_transpose<<<dim3(256, N_EXP), 256, 0, stream>>>(W2, W2T, H_DIM, O_DIM);
  k_router<<<N_TOK / 4, 256, 0, stream>>>(x, Wr, br, expert_id, xbf);
  k_count<<<N_TOK / 1024, 1024, 0, stream>>>(expert_id, counts);
  k_scan<<<1, 256, 0, stream>>>(counts, offsets, cursor, table);
  k_scatter<<<N_TOK / 512, 512, 0, stream>>>(expert_id, cursor, idx_list);

  for (int ch = 0; ch < nch; ++ch) {
    k_gemm1<<<MAX_TILES * nt1, 512, 0, stream>>>(xbf, W1T, b1, counts, offsets,
                                                 table, idx_list, Hperm, nt1, ch, hchunk);
    k_gemm2<<<MAX_TILES * 2, 512, 0, stream>>>(Hperm, W2T, b2, counts, offsets,
                                               table, idx_list, out, ch, hchunk, ch > 0);
  }
}

// Round 6
// 394.279 us; speedup vs baseline: 4.2337x; 1.0093x over previous
//
#include <hip/hip_runtime.h>
#include <stdint.h>

#define N_TOK 32768
#define D_IN  512
#define H_DIM 2048
#define O_DIM 512
#define N_EXP 8
// gemm1 tiles: M=128, N=256, BK=64. table128 padded to 272 (= 8 XCDs * 34)
#define NT128P 272
#define TPX    34
// gemm2 tiles: M=160, N=512, BK=32. sum ceil(cnt/160) <= 204+8 = 212 <= 224
#define BM2    160
#define NT160  224

typedef __bf16 bf16x8 __attribute__((ext_vector_type(8)));
typedef float  f32x4  __attribute__((ext_vector_type(4)));
typedef unsigned int u32x4 __attribute__((ext_vector_type(4)));

struct alignas(8) us4 { unsigned short x, y, z, w; };

#define FENCE() asm volatile("" ::: "memory")
#define BAR()   do { FENCE(); __builtin_amdgcn_s_barrier(); FENCE(); } while (0)
#define WAITV(N) asm volatile("s_waitcnt vmcnt(" #N ")" ::: "memory")

__device__ __forceinline__ unsigned short f2bf(float f) {
  union { float f; unsigned u; } v; v.f = f;
  unsigned r = v.u + 0x7FFFu + ((v.u >> 16) & 1u);  // round-to-nearest-even
  return (unsigned short)(r >> 16);
}

// async global->LDS; dest = wave-uniform base + lane*size (HW)
__device__ __forceinline__ void gll16(const void* src, void* lds_dst) {
  __builtin_amdgcn_global_load_lds(
      (const __attribute__((address_space(1))) void*)src,
      (__attribute__((address_space(3))) void*)lds_dst, 16, 0, 0);
}
__device__ __forceinline__ void gll4(const void* src, void* lds_dst) {
  __builtin_amdgcn_global_load_lds(
      (const __attribute__((address_space(1))) void*)src,
      (__attribute__((address_space(3))) void*)lds_dst, 4, 0, 0);
}

// ---------------- init ----------------
__global__ void k_init(int* counts) {
  if (threadIdx.x < N_EXP) counts[threadIdx.x] = 0;
}

// ---------------- weight convert + transpose to bf16: W (E,R,C) f32 -> WT (E,C,R) bf16 ----------------
__global__ void k_transpose(const float* __restrict__ W, unsigned short* __restrict__ WT,
                            int R, int C) {
  __shared__ unsigned short tile[64][72];
  int e = blockIdx.y;
  const float* src = W + (size_t)e * R * C;
  unsigned short* dst = WT + (size_t)e * R * C;
  int tilesC = C >> 6;
  int tc = (blockIdx.x % tilesC) << 6;
  int tr = (blockIdx.x / tilesC) << 6;
  int tid = threadIdx.x;
  int rq = tid >> 4;
  int cq = tid & 15;
#pragma unroll
  for (int q = 0; q < 4; ++q) {
    int r = q * 16 + rq;
    float4 v = *(const float4*)(src + (size_t)(tr + r) * C + tc + cq * 4);
    us4 b;
    b.x = f2bf(v.x); b.y = f2bf(v.y); b.z = f2bf(v.z); b.w = f2bf(v.w);
    *(us4*)&tile[r][cq * 4] = b;
  }
  __syncthreads();
#pragma unroll
  for (int q = 0; q < 4; ++q) {
    int cc = q * 16 + rq;
    int rr = cq * 4;
    us4 o;
    o.x = tile[rr + 0][cc]; o.y = tile[rr + 1][cc];
    o.z = tile[rr + 2][cc]; o.w = tile[rr + 3][cc];
    *(us4*)(dst + (size_t)(tc + cc) * R + tr + rr) = o;
  }
}

// ---------------- router (fp32) + fused x -> bf16 cast; NO atomics ----------------
__global__ void k_router(const float* __restrict__ x, const float* __restrict__ Wr,
                         const float* __restrict__ br, int* __restrict__ expert_id,
                         unsigned short* __restrict__ xbf) {
  int token = blockIdx.x * 4 + (threadIdx.x >> 6);
  int lane  = threadIdx.x & 63;
  const float* xr = x + (size_t)token * D_IN;
  float acc[N_EXP];
#pragma unroll
  for (int e = 0; e < N_EXP; ++e) acc[e] = 0.f;
#pragma unroll
  for (int j = 0; j < 2; ++j) {
    int i0 = lane * 8 + j * 4;
    float4 xv = *(const float4*)(xr + i0);
    us4 bb;
    bb.x = f2bf(xv.x); bb.y = f2bf(xv.y); bb.z = f2bf(xv.z); bb.w = f2bf(xv.w);
    *(us4*)(xbf + (size_t)token * D_IN + i0) = bb;
    float xs[4] = {xv.x, xv.y, xv.z, xv.w};
#pragma unroll
    for (int u = 0; u < 4; ++u) {
      const float4* wr = (const float4*)(Wr + (size_t)(i0 + u) * N_EXP);
      float4 w0 = wr[0], w1 = wr[1];
      acc[0] += xs[u] * w0.x; acc[1] += xs[u] * w0.y;
      acc[2] += xs[u] * w0.z; acc[3] += xs[u] * w0.w;
      acc[4] += xs[u] * w1.x; acc[5] += xs[u] * w1.y;
      acc[6] += xs[u] * w1.z; acc[7] += xs[u] * w1.w;
    }
  }
#pragma unroll
  for (int off = 32; off > 0; off >>= 1) {
#pragma unroll
    for (int e = 0; e < N_EXP; ++e) acc[e] += __shfl_xor(acc[e], off, 64);
  }
  if (lane == 0) {
    float best = acc[0] + br[0]; int bi = 0;
#pragma unroll
    for (int e = 1; e < N_EXP; ++e) {
      float v = acc[e] + br[e];
      if (v > best) { best = v; bi = e; }   // first max wins (matches top_k)
    }
    expert_id[token] = bi;
  }
}

// ---------------- count: LDS histogram ----------------
__global__ void k_count(const int* __restrict__ expert_id, int* __restrict__ counts) {
  __shared__ int lcnt[N_EXP];
  int tid = threadIdx.x;
  if (tid < N_EXP) lcnt[tid] = 0;
  __syncthreads();
  int e = expert_id[blockIdx.x * 1024 + tid];
  atomicAdd(&lcnt[e], 1);
  __syncthreads();
  if (tid < N_EXP) atomicAdd(&counts[tid], lcnt[tid]);
}

// ---------------- scan: offsets + table128 (expert-major) + table160 (XCD-interleaved) ----------------
__global__ void k_scan(const int* __restrict__ counts, int* __restrict__ offsets,
                       int* __restrict__ cursor, int2* __restrict__ table128,
                       int2* __restrict__ table160) {
  int i = threadIdx.x;   // 512 threads
  int s = 0, ts = 0, myexp = -1, myt = -1;
#pragma unroll
  for (int e = 0; e < N_EXP; ++e) {
    int c = counts[e];
    int tc = (c + 127) >> 7;
    if (i == e) { offsets[e] = s; cursor[e] = s; }
    if (i >= ts && i < ts + tc) { myexp = e; myt = i - ts; }
    s += c; ts += tc;
  }
  if (i < NT128P) table128[i] = make_int2(myexp, myt);
  if (i == 0) {
    int tc[N_EXP], done[N_EXP];
    for (int e = 0; e < N_EXP; ++e) { tc[e] = (counts[e] + BM2 - 1) / BM2; done[e] = 0; }
    for (int k = 0; k < NT160; ++k) {
      int e = -1, pref = k & 7;
      if (done[pref] < tc[pref]) e = pref;
      else {
        int bv = 0;
        for (int j = 0; j < N_EXP; ++j) {
          int r = tc[j] - done[j];
          if (r > bv) { bv = r; e = j; }
        }
      }
      if (e >= 0) { table160[k] = make_int2(e, done[e]); done[e]++; }
      else        { table160[k] = make_int2(-1, -1); }
    }
  }
}

// ---------------- scatter: LDS histogram, one block-atomic per expert ----------------
__global__ void k_scatter(const int* __restrict__ expert_id, int* __restrict__ cursor,
                          int* __restrict__ idx_list) {
  __shared__ int lcnt[N_EXP], lbase[N_EXP];
  int tid = threadIdx.x;
  int i = blockIdx.x * 512 + tid;
  if (tid < N_EXP) lcnt[tid] = 0;
  __syncthreads();
  int e = expert_id[i];
  int lpos = atomicAdd(&lcnt[e], 1);
  __syncthreads();
  if (tid < N_EXP) lbase[tid] = atomicAdd(&cursor[tid], lcnt[tid]);
  __syncthreads();
  idx_list[lbase[e] + lpos] = i;
}

// ---------------- GEMM1: Hperm = relu(Xg @ W1T^T + b1); 128x256 tile, BK=64 ----------------
// XCD-grouped: bid%8 = XCD, the nt ntile-blocks of one tile are consecutive on one XCD.
__launch_bounds__(512, 2)
__global__ void k_gemm1(const unsigned short* __restrict__ xbf,
                        const unsigned short* __restrict__ W1T,   // (E, H, D) bf16
                        const float* __restrict__ b1,
                        const int* __restrict__ counts, const int* __restrict__ offsets,
                        const int2* __restrict__ table128, const int* __restrict__ idx_list,
                        unsigned short* __restrict__ Hperm,       // (N_TOK, hchunk) bf16
                        int nt1, int ch, int hchunk) {
  int xcd = blockIdx.x & 7;
  int s   = blockIdx.x >> 3;
  int tile  = xcd * TPX + s / nt1;
  int ntile = s % nt1;
  int2 et = table128[tile];
  int e = et.x;
  if (e < 0) return;
  int base   = offsets[e] + et.y * 128;
  int mvalid = min(128, counts[e] - et.y * 128);

  __shared__ __align__(16) unsigned char lds_raw[98304];  // A:2x16K @0, B:2x32K @32K

  int tid = threadIdx.x, w = tid >> 6, lane = tid & 63;
  int l15 = lane & 15, l4 = lane >> 4;
  int wr = w >> 2, wc = w & 3;
  int n0 = ch * hchunk + ntile * 256;

  unsigned offA[2], offB[4];
#pragma unroll
  for (int q = 0; q < 2; ++q) {
    int d   = q * 8192 + w * 1024 + lane * 16;
    int row = d >> 7;
    int bs  = (d & 127) ^ ((row & 7) << 4);
    int tok = idx_list[base + min(row, mvalid - 1)];
    offA[q] = (unsigned)tok * (D_IN * 2) + bs;
  }
#pragma unroll
  for (int q = 0; q < 4; ++q) {
    int d   = q * 8192 + w * 1024 + lane * 16;
    int n   = d >> 7;
    int bs  = (d & 127) ^ ((n & 7) << 4);
    offB[q] = (unsigned)(e * H_DIM + n0 + n) * (D_IN * 2) + bs;
  }

  f32x4 acc[4][4];
#pragma unroll
  for (int a = 0; a < 4; ++a)
#pragma unroll
    for (int b = 0; b < 4; ++b) acc[a][b] = (f32x4){0.f, 0.f, 0.f, 0.f};

#define STAGE1(buf, kstep) do {                                              \
    unsigned kb = (unsigned)(kstep) * 128u;                                  \
    unsigned char* da = lds_raw + (unsigned)(buf) * 16384u;                  \
    unsigned char* db = lds_raw + 32768u + (unsigned)(buf) * 32768u;         \
    _Pragma("unroll")                                                        \
    for (int q = 0; q < 2; ++q)                                              \
      gll16((const char*)xbf + offA[q] + kb, da + q * 8192 + w * 1024);      \
    _Pragma("unroll")                                                        \
    for (int q = 0; q < 4; ++q)                                              \
      gll16((const char*)W1T + offB[q] + kb, db + q * 8192 + w * 1024);      \
  } while (0)

#define COMPUTE1(buf) do {                                                   \
    const unsigned char* A = lds_raw + (unsigned)(buf) * 16384u;             \
    const unsigned char* B = lds_raw + 32768u + (unsigned)(buf) * 32768u;    \
    __builtin_amdgcn_s_setprio(1);                                           \
    _Pragma("unroll")                                                        \
    for (int ks = 0; ks < 2; ++ks) {                                         \
      int kb = ks * 64 + l4 * 16;                                            \
      bf16x8 bfr[4];                                                         \
      _Pragma("unroll")                                                      \
      for (int cf = 0; cf < 4; ++cf) {                                       \
        int n = wc * 64 + cf * 16 + l15;                                     \
        bfr[cf] = *(const bf16x8*)(B + n * 128 + (kb ^ ((n & 7) << 4)));     \
      }                                                                      \
      _Pragma("unroll")                                                      \
      for (int rf = 0; rf < 4; ++rf) {                                       \
        int m = wr * 64 + rf * 16 + l15;                                     \
        bf16x8 af = *(const bf16x8*)(A + m * 128 + (kb ^ ((m & 7) << 4)));   \
        _Pragma("unroll")                                                    \
        for (int cf = 0; cf < 4; ++cf)                                       \
          acc[rf][cf] = __builtin_amdgcn_mfma_f32_16x16x32_bf16(af, bfr[cf], acc[rf][cf], 0, 0, 0); \
      }                                                                      \
    }                                                                        \
    __builtin_amdgcn_s_setprio(0);                                           \
  } while (0)

  const int NK = D_IN / 64;  // 8
  STAGE1(0, 0);
  STAGE1(1, 1);
  WAITV(6);
  BAR();
  for (int k = 0; k < NK - 1; ++k) {
    COMPUTE1(k & 1);
    BAR();
    if (k + 2 < NK) { STAGE1(k & 1, k + 2); WAITV(6); }
    else            { WAITV(0); }
    BAR();
  }
  COMPUTE1((NK - 1) & 1);
  BAR();

  // epilogue: bias+relu -> LDS C-tile (128 rows x 512 B, XOR swz) -> coalesced 16B stores
#pragma unroll
  for (int cf = 0; cf < 4; ++cf) {
    int col = wc * 64 + cf * 16 + l15;
    float bv = b1[(size_t)e * H_DIM + n0 + col];
#pragma unroll
    for (int rf = 0; rf < 4; ++rf) {
#pragma unroll
      for (int j = 0; j < 4; ++j) {
        int row = wr * 64 + rf * 16 + l4 * 4 + j;
        float v = fmaxf(acc[rf][cf][j] + bv, 0.f);
        *(unsigned short*)(lds_raw + row * 512 + ((col * 2) ^ ((row & 7) << 4))) = f2bf(v);
      }
    }
  }
  BAR();
  {
    int row = tid >> 2;          // 0..127
    int seg = (tid & 3) * 128;   // 128B segment within the 512B row
    if (row < mvalid) {
      int swz = (row & 7) << 4;
      char* gdst = (char*)Hperm + ((size_t)(base + row) * hchunk + ntile * 256) * 2 + seg;
      const unsigned char* lsrc = lds_raw + row * 512;
#pragma unroll
      for (int i = 0; i < 8; ++i) {
        u32x4 v = *(const u32x4*)(lsrc + ((seg + i * 16) ^ swz));
        *(u32x4*)(gdst + i * 16) = v;
      }
    }
  }
#undef STAGE1
#undef COMPUTE1
}

// ---------------- GEMM2: out = Hperm @ W2T^T (+ b2); 160x512 tile, BK=32, grid<=224 ----------------
__launch_bounds__(512, 2)
__global__ void k_gemm2(const unsigned short* __restrict__ Hperm,  // (N_TOK, hchunk) bf16
                        const unsigned short* __restrict__ W2T,    // (E, O, H) bf16
                        const float* __restrict__ b2,
                        const int* __restrict__ counts, const int* __restrict__ offsets,
                        const int2* __restrict__ table160, const int* __restrict__ idx_list,
                        float* __restrict__ out,
                        int ch, int hchunk, int accumulate) {
  int2 et = table160[blockIdx.x];
  int e = et.x;
  if (e < 0) return;
  int base   = offsets[e] + et.y * BM2;
  int mvalid = min(BM2, counts[e] - et.y * BM2);

  __shared__ __align__(16) unsigned char lds_raw[86016];  // A:2x10K @0, B:2x32K @20480

  int tid = threadIdx.x, w = tid >> 6, lane = tid & 63;
  int l15 = lane & 15, l4 = lane >> 4;
  int wr = w >> 2, wc = w & 3;
  const unsigned hrow_bytes = (unsigned)hchunk * 2;

  unsigned offA[5], offB[4];
#pragma unroll
  for (int q = 0; q < 5; ++q) {
    int d   = q * 2048 + w * 256 + lane * 4;
    int row = d >> 6;
    int bs  = (d & 63) ^ ((row & 3) << 4);
    offA[q] = (unsigned)min(base + row, N_TOK - 1) * hrow_bytes + bs;
  }
#pragma unroll
  for (int q = 0; q < 4; ++q) {
    int d  = q * 8192 + w * 1024 + lane * 16;
    int n  = d >> 6;
    int bs = (d & 63) ^ ((n & 3) << 4);
    offB[q] = (unsigned)(e * O_DIM + n) * (H_DIM * 2) + (unsigned)ch * hchunk * 2 + bs;
  }

  f32x4 acc[5][8];
#pragma unroll
  for (int a = 0; a < 5; ++a)
#pragma unroll
    for (int b = 0; b < 8; ++b) acc[a][b] = (f32x4){0.f, 0.f, 0.f, 0.f};

#define STAGE2(buf, kstep) do {                                              \
    unsigned kb = (unsigned)(kstep) * 64u;                                   \
    unsigned char* da = lds_raw + (unsigned)(buf) * 10240u;                  \
    unsigned char* db = lds_raw + 20480u + (unsigned)(buf) * 32768u;         \
    _Pragma("unroll")                                                        \
    for (int q = 0; q < 5; ++q)                                              \
      gll4((const char*)Hperm + offA[q] + kb, da + q * 2048 + w * 256);      \
    _Pragma("unroll")                                                        \
    for (int q = 0; q < 4; ++q)                                              \
      gll16((const char*)W2T + offB[q] + kb, db + q * 8192 + w * 1024);      \
  } while (0)

#define COMPUTE2(buf) do {                                                   \
    const unsigned char* A = lds_raw + (unsigned)(buf) * 10240u;             \
    const unsigned char* B = lds_raw + 20480u + (unsigned)(buf) * 32768u;    \
    bf16x8 bfr[8];                                                           \
    _Pragma("unroll")                                                        \
    for (int cf = 0; cf < 8; ++cf) {                                         \
      int n = wc * 128 + cf * 16 + l15;                                      \
      bfr[cf] = *(const bf16x8*)(B + n * 64 + ((l4 * 16) ^ ((n & 3) << 4))); \
    }                                                                        \
    __builtin_amdgcn_s_setprio(1);                                           \
    _Pragma("unroll")                                                        \
    for (int rf = 0; rf < 5; ++rf) {                                         \
      int m = wr * 80 + rf * 16 + l15;                                       \
      bf16x8 af = *(const bf16x8*)(A + m * 64 + ((l4 * 16) ^ ((m & 3) << 4))); \
      _Pragma("unroll")                                                      \
      for (int cf = 0; cf < 8; ++cf)                                         \
        acc[rf][cf] = __builtin_amdgcn_mfma_f32_16x16x32_bf16(af, bfr[cf], acc[rf][cf], 0, 0, 0); \
    }                                                                        \
    __builtin_amdgcn_s_setprio(0);                                           \
  } while (0)

  const int NK = hchunk / 32;
  STAGE2(0, 0);
  STAGE2(1, 1);
  WAITV(9);
  BAR();
  for (int k = 0; k < NK - 1; ++k) {
    COMPUTE2(k & 1);
    BAR();
    if (k + 2 < NK) { STAGE2(k & 1, k + 2); WAITV(9); }
    else            { WAITV(0); }
    BAR();
  }
  COMPUTE2((NK - 1) & 1);

  // epilogue: scatter rows to out (fp32), bias on first chunk
#pragma unroll
  for (int cf = 0; cf < 8; ++cf) {
    int o = wc * 128 + cf * 16 + l15;
    float bv = b2[(size_t)e * O_DIM + o];
#pragma unroll
    for (int rf = 0; rf < 5; ++rf) {
#pragma unroll
      for (int j = 0; j < 4; ++j) {
        int row = wr * 80 + rf * 16 + l4 * 4 + j;
        if (row < mvalid) {
          int tok = idx_list[base + row];
          float* p = out + (size_t)tok * O_DIM + o;
          if (accumulate) *p = *p + acc[rf][cf][j];
          else            *p = acc[rf][cf][j] + bv;
        }
      }
    }
  }
#undef STAGE2
#undef COMPUTE2
}

// ---------------- launch ----------------
extern "C" void kernel_launch(void* const* d_in, const int* in_sizes, int n_in,
                              void* d_out, int out_size, void* d_ws, size_t ws_size,
                              hipStream_t stream) {
  const float* x  = (const float*)d_in[0];
  const float* Wr = (const float*)d_in[1];
  const float* br = (const float*)d_in[2];
  const float* W1 = (const float*)d_in[3];
  const float* b1 = (const float*)d_in[4];
  const float* W2 = (const float*)d_in[5];
  const float* b2 = (const float*)d_in[6];
  float* out = (float*)d_out;

  char* ws = (char*)d_ws;
  int*  counts    = (int*)(ws + 0);
  int*  offsets   = (int*)(ws + 64);
  int*  cursor    = (int*)(ws + 128);
  int2* table128  = (int2*)(ws + 256);                 // 272*8 = 2176 B
  int2* table160  = (int2*)(ws + 2560);                // 224*8 = 1792 B
  int*  expert_id = (int*)(ws + 8192);                 // 128 KB
  int*  idx_list  = (int*)(ws + 8192 + N_TOK * 4);     // 128 KB
  size_t off = 8192 + 2 * (size_t)N_TOK * 4;
  unsigned short* xbf = (unsigned short*)(ws + off);   // 32 MB
  off += (size_t)N_TOK * D_IN * 2;
  unsigned short* W1T = (unsigned short*)(ws + off);   // 16 MB
  off += (size_t)N_EXP * H_DIM * D_IN * 2;
  unsigned short* W2T = (unsigned short*)(ws + off);   // 16 MB
  off += (size_t)N_EXP * H_DIM * O_DIM * 2;
  unsigned short* Hperm = (unsigned short*)(ws + off);

  // largest H-chunk that fits remaining workspace (256-col floor)
  int hchunk = 2048;
  while (hchunk > 256 && off + (size_t)N_TOK * hchunk * 2 > ws_size) hchunk >>= 1;
  int nch = H_DIM / hchunk;
  int nt1 = hchunk / 256;

  k_init<<<1, 64, 0, stream>>>(counts);
  k_transpose<<<dim3(256, N_EXP), 256, 0, stream>>>(W1, W1T, D_IN, H_DIM);
  k_transpose<<<dim3(256, N_EXP), 256, 0, stream>>>(W2, W2T, H_DIM, O_DIM);
  k_router<<<N_TOK / 4, 256, 0, stream>>>(x, Wr, br, expert_id, xbf);
  k_count<<<N_TOK / 1024, 1024, 0, stream>>>(expert_id, counts);
  k_scan<<<1, 512, 0, stream>>>(counts, offsets, cursor, table128, table160);
  k_scatter<<<N_TOK / 512, 512, 0, stream>>>(expert_id, cursor, idx_list);

  for (int ch = 0; ch < nch; ++ch) {
    k_gemm1<<<NT128P * nt1, 512, 0, stream>>>(xbf, W1T, b1, counts, offsets,
                                              table128, idx_list, Hperm, nt1, ch, hchunk);
    k_gemm2<<<NT160, 512, 0, stream>>>(Hperm, W2T, b2, counts, offsets,
                                       table160, idx_list, out, ch, hchunk, ch > 0);
  }
}

// Round 7
// 353.917 us; speedup vs baseline: 4.7165x; 1.1140x over previous
//
#include <hip/hip_runtime.h>
#include <stdint.h>

#define N_TOK 32768
#define D_IN  512
#define H_DIM 2048
#define O_DIM 512
#define N_EXP 8
// tiles: M=128 rows of permuted tokens. sum ceil(cnt/128) <= 256+7; pad to 272 = 8 XCDs * 34
#define NTILES 272
#define TPX    34

typedef __bf16 bf16x8 __attribute__((ext_vector_type(8)));
typedef float  f32x4  __attribute__((ext_vector_type(4)));
typedef unsigned int u32x4 __attribute__((ext_vector_type(4)));

struct alignas(8) us4 { unsigned short x, y, z, w; };

#define FENCE() asm volatile("" ::: "memory")
#define BAR()   do { FENCE(); __builtin_amdgcn_s_barrier(); FENCE(); } while (0)
#define WAITV0  asm volatile("s_waitcnt vmcnt(0)" ::: "memory")

__device__ __forceinline__ unsigned short f2bf(float f) {
  union { float f; unsigned u; } v; v.f = f;
  unsigned r = v.u + 0x7FFFu + ((v.u >> 16) & 1u);  // round-to-nearest-even
  return (unsigned short)(r >> 16);
}

// async global->LDS, 16B/lane; LDS dest = wave-uniform base + lane*16 (HW)
__device__ __forceinline__ void gll16(const void* src, void* lds_dst) {
  __builtin_amdgcn_global_load_lds(
      (const __attribute__((address_space(1))) void*)src,
      (__attribute__((address_space(3))) void*)lds_dst, 16, 0, 0);
}

// ---------------- init ----------------
__global__ void k_init(int* counts) {
  if (threadIdx.x < N_EXP) counts[threadIdx.x] = 0;
}

// ---------------- weight convert + transpose to bf16: W (E,R,C) f32 -> WT (E,C,R) bf16 ----------------
__global__ void k_transpose(const float* __restrict__ W, unsigned short* __restrict__ WT,
                            int R, int C) {
  __shared__ unsigned short tile[64][72];
  int e = blockIdx.y;
  const float* src = W + (size_t)e * R * C;
  unsigned short* dst = WT + (size_t)e * R * C;
  int tilesC = C >> 6;
  int tc = (blockIdx.x % tilesC) << 6;
  int tr = (blockIdx.x / tilesC) << 6;
  int tid = threadIdx.x;
  int rq = tid >> 4;
  int cq = tid & 15;
#pragma unroll
  for (int q = 0; q < 4; ++q) {
    int r = q * 16 + rq;
    float4 v = *(const float4*)(src + (size_t)(tr + r) * C + tc + cq * 4);
    us4 b;
    b.x = f2bf(v.x); b.y = f2bf(v.y); b.z = f2bf(v.z); b.w = f2bf(v.w);
    *(us4*)&tile[r][cq * 4] = b;
  }
  __syncthreads();
#pragma unroll
  for (int q = 0; q < 4; ++q) {
    int cc = q * 16 + rq;
    int rr = cq * 4;
    us4 o;
    o.x = tile[rr + 0][cc]; o.y = tile[rr + 1][cc];
    o.z = tile[rr + 2][cc]; o.w = tile[rr + 3][cc];
    *(us4*)(dst + (size_t)(tc + cc) * R + tr + rr) = o;
  }
}

// ---------------- router (fp32) + fused x -> bf16 cast; NO atomics ----------------
__global__ void k_router(const float* __restrict__ x, const float* __restrict__ Wr,
                         const float* __restrict__ br, int* __restrict__ expert_id,
                         unsigned short* __restrict__ xbf) {
  int token = blockIdx.x * 4 + (threadIdx.x >> 6);
  int lane  = threadIdx.x & 63;
  const float* xr = x + (size_t)token * D_IN;
  float acc[N_EXP];
#pragma unroll
  for (int e = 0; e < N_EXP; ++e) acc[e] = 0.f;
#pragma unroll
  for (int j = 0; j < 2; ++j) {
    int i0 = lane * 8 + j * 4;
    float4 xv = *(const float4*)(xr + i0);
    us4 bb;
    bb.x = f2bf(xv.x); bb.y = f2bf(xv.y); bb.z = f2bf(xv.z); bb.w = f2bf(xv.w);
    *(us4*)(xbf + (size_t)token * D_IN + i0) = bb;
    float xs[4] = {xv.x, xv.y, xv.z, xv.w};
#pragma unroll
    for (int u = 0; u < 4; ++u) {
      const float4* wr = (const float4*)(Wr + (size_t)(i0 + u) * N_EXP);
      float4 w0 = wr[0], w1 = wr[1];
      acc[0] += xs[u] * w0.x; acc[1] += xs[u] * w0.y;
      acc[2] += xs[u] * w0.z; acc[3] += xs[u] * w0.w;
      acc[4] += xs[u] * w1.x; acc[5] += xs[u] * w1.y;
      acc[6] += xs[u] * w1.z; acc[7] += xs[u] * w1.w;
    }
  }
#pragma unroll
  for (int off = 32; off > 0; off >>= 1) {
#pragma unroll
    for (int e = 0; e < N_EXP; ++e) acc[e] += __shfl_xor(acc[e], off, 64);
  }
  if (lane == 0) {
    float best = acc[0] + br[0]; int bi = 0;
#pragma unroll
    for (int e = 1; e < N_EXP; ++e) {
      float v = acc[e] + br[e];
      if (v > best) { best = v; bi = e; }   // first max wins (matches top_k)
    }
    expert_id[token] = bi;
  }
}

// ---------------- count: LDS histogram ----------------
__global__ void k_count(const int* __restrict__ expert_id, int* __restrict__ counts) {
  __shared__ int lcnt[N_EXP];
  int tid = threadIdx.x;
  if (tid < N_EXP) lcnt[tid] = 0;
  __syncthreads();
  int e = expert_id[blockIdx.x * 1024 + tid];
  atomicAdd(&lcnt[e], 1);
  __syncthreads();
  if (tid < N_EXP) atomicAdd(&counts[tid], lcnt[tid]);
}

// ---------------- scan: offsets + cursors + expert-major 128-row tile table ----------------
__global__ void k_scan(const int* __restrict__ counts, int* __restrict__ offsets,
                       int* __restrict__ cursor, int2* __restrict__ table) {
  int i = threadIdx.x;   // 512 threads
  int s = 0, ts = 0, myexp = -1, myt = -1;
#pragma unroll
  for (int e = 0; e < N_EXP; ++e) {
    int c = counts[e];
    int tc = (c + 127) >> 7;
    if (i == e) { offsets[e] = s; cursor[e] = s; }
    if (i >= ts && i < ts + tc) { myexp = e; myt = i - ts; }
    s += c; ts += tc;
  }
  if (i < NTILES) table[i] = make_int2(myexp, myt);
}

// ---------------- scatter: LDS histogram, one block-atomic per expert ----------------
__global__ void k_scatter(const int* __restrict__ expert_id, int* __restrict__ cursor,
                          int* __restrict__ idx_list) {
  __shared__ int lcnt[N_EXP], lbase[N_EXP];
  int tid = threadIdx.x;
  int i = blockIdx.x * 512 + tid;
  if (tid < N_EXP) lcnt[tid] = 0;
  __syncthreads();
  int e = expert_id[i];
  int lpos = atomicAdd(&lcnt[e], 1);
  __syncthreads();
  if (tid < N_EXP) lbase[tid] = atomicAdd(&cursor[tid], lcnt[tid]);
  __syncthreads();
  idx_list[lbase[e] + lpos] = i;
}

// ================= m97-replica GEMM core: 128x128 tile, BK=64, 4 waves, 64KB dbuf LDS ===============
// 2 blocks/CU (latency hiding via inter-block overlap). Issue-early stage, vmcnt(0)+bar per step.

// ---------------- GEMM1: Hperm = relu(Xg @ W1T^T + b1) ----------------
__launch_bounds__(256, 2)
__global__ void k_gemm1(const unsigned short* __restrict__ xbf,
                        const unsigned short* __restrict__ W1T,   // (E, H, D) bf16
                        const float* __restrict__ b1,
                        const int* __restrict__ counts, const int* __restrict__ offsets,
                        const int2* __restrict__ table, const int* __restrict__ idx_list,
                        unsigned short* __restrict__ Hperm,       // (N_TOK, hchunk) bf16
                        int nt1, int ch, int hchunk) {
  int xcd = blockIdx.x & 7;
  int s   = blockIdx.x >> 3;
  int tile  = xcd + 8 * (s / nt1);      // XCD x owns tiles = x (mod 8): A-tile + panel L2-local
  int ntile = s % nt1;
  int2 et = table[tile];
  int e = et.x;
  if (e < 0) return;
  int base   = offsets[e] + et.y * 128;
  int mvalid = min(128, counts[e] - et.y * 128);

  __shared__ __align__(16) unsigned char lds[65536];  // A0,A1 @0; B0,B1 @32K; epilogue bounce @0

  int tid = threadIdx.x, w = tid >> 6, lane = tid & 63;
  int l15 = lane & 15, l4 = lane >> 4;
  int wr = w >> 1, wc = w & 1;
  int n0 = ch * hchunk + ntile * 128;   // global H col base

  unsigned offA[4], offB[4];
#pragma unroll
  for (int q = 0; q < 4; ++q) {
    int d   = q * 4096 + w * 1024 + lane * 16;   // linear dest byte in 16KB tile
    int row = d >> 7;
    int bs  = (d & 127) ^ ((row & 7) << 4);      // inverse-swizzled source byte
    int tok = idx_list[base + min(row, mvalid - 1)];
    offA[q] = (unsigned)tok * (D_IN * 2) + bs;
    offB[q] = (unsigned)(e * H_DIM + n0 + row) * (D_IN * 2) + bs;
  }

  f32x4 acc[4][4];
#pragma unroll
  for (int a = 0; a < 4; ++a)
#pragma unroll
    for (int b = 0; b < 4; ++b) acc[a][b] = (f32x4){0.f, 0.f, 0.f, 0.f};

#define STAGE1(buf, kstep) do {                                              \
    unsigned kb = (unsigned)(kstep) * 128u;                                  \
    unsigned char* da = lds + (unsigned)(buf) * 16384u;                      \
    unsigned char* db = lds + 32768u + (unsigned)(buf) * 16384u;             \
    _Pragma("unroll")                                                        \
    for (int q = 0; q < 4; ++q) {                                            \
      gll16((const char*)xbf + offA[q] + kb, da + q * 4096 + w * 1024);      \
      gll16((const char*)W1T + offB[q] + kb, db + q * 4096 + w * 1024);      \
    }                                                                        \
  } while (0)

#define COMPUTE1(buf) do {                                                   \
    const unsigned char* A = lds + (unsigned)(buf) * 16384u;                 \
    const unsigned char* B = lds + 32768u + (unsigned)(buf) * 16384u;        \
    __builtin_amdgcn_s_setprio(1);                                           \
    _Pragma("unroll")                                                        \
    for (int ks = 0; ks < 2; ++ks) {                                         \
      int kb = ks * 64 + l4 * 16;                                            \
      bf16x8 bfr[4];                                                         \
      _Pragma("unroll")                                                      \
      for (int nf = 0; nf < 4; ++nf) {                                       \
        int n = wc * 64 + nf * 16 + l15;                                     \
        bfr[nf] = *(const bf16x8*)(B + n * 128 + (kb ^ ((n & 7) << 4)));     \
      }                                                                      \
      _Pragma("unroll")                                                      \
      for (int mf = 0; mf < 4; ++mf) {                                       \
        int m = wr * 64 + mf * 16 + l15;                                     \
        bf16x8 af = *(const bf16x8*)(A + m * 128 + (kb ^ ((m & 7) << 4)));   \
        _Pragma("unroll")                                                    \
        for (int nf = 0; nf < 4; ++nf)                                       \
          acc[mf][nf] = __builtin_amdgcn_mfma_f32_16x16x32_bf16(af, bfr[nf], acc[mf][nf], 0, 0, 0); \
      }                                                                      \
    }                                                                        \
    __builtin_amdgcn_s_setprio(0);                                           \
  } while (0)

  const int NK = D_IN / 64;  // 8
  STAGE1(0, 0);
  WAITV0;
  BAR();
  for (int t = 0; t < NK; ++t) {
    if (t + 1 < NK) { STAGE1((t + 1) & 1, t + 1); __builtin_amdgcn_sched_barrier(0); }
    COMPUTE1(t & 1);
    WAITV0;          // next tile landed (issued one full compute ago)
    BAR();
  }

  // epilogue: bias+relu -> bf16 LDS bounce (128 rows x 256 B, XOR swz) -> coalesced stores
#pragma unroll
  for (int nf = 0; nf < 4; ++nf) {
    int col = wc * 64 + nf * 16 + l15;
    float bv = b1[(size_t)e * H_DIM + n0 + col];
#pragma unroll
    for (int mf = 0; mf < 4; ++mf) {
#pragma unroll
      for (int j = 0; j < 4; ++j) {
        int row = wr * 64 + mf * 16 + l4 * 4 + j;
        float v = fmaxf(acc[mf][nf][j] + bv, 0.f);
        *(unsigned short*)(lds + row * 256 + ((col * 2) ^ ((row & 7) << 4))) = f2bf(v);
      }
    }
  }
  BAR();
  {
    int row = tid >> 1;          // 0..127
    int seg = (tid & 1) * 128;   // 128B half of the 256B row
    if (row < mvalid) {
      int swz = (row & 7) << 4;
      char* gdst = (char*)Hperm + ((size_t)(base + row) * hchunk + ntile * 128) * 2 + seg;
      const unsigned char* lsrc = lds + row * 256;
#pragma unroll
      for (int i = 0; i < 8; ++i) {
        u32x4 v = *(const u32x4*)(lsrc + ((seg + i * 16) ^ swz));
        *(u32x4*)(gdst + i * 16) = v;
      }
    }
  }
#undef STAGE1
#undef COMPUTE1
}

// ---------------- GEMM2: out = Hperm @ W2T^T (+ b2) ----------------
__launch_bounds__(256, 2)
__global__ void k_gemm2(const unsigned short* __restrict__ Hperm,  // (N_TOK, hchunk) bf16
                        const unsigned short* __restrict__ W2T,    // (E, O, H) bf16
                        const float* __restrict__ b2,
                        const int* __restrict__ counts, const int* __restrict__ offsets,
                        const int2* __restrict__ table, const int* __restrict__ idx_list,
                        float* __restrict__ out,
                        int ch, int hchunk, int accumulate) {
  int xcd = blockIdx.x & 7;
  int s   = blockIdx.x >> 3;
  int tile  = xcd + 8 * (s >> 2);
  int ntile = s & 3;
  int2 et = table[tile];
  int e = et.x;
  if (e < 0) return;
  int base   = offsets[e] + et.y * 128;
  int mvalid = min(128, counts[e] - et.y * 128);

  __shared__ __align__(16) unsigned char lds[65536];

  int tid = threadIdx.x, w = tid >> 6, lane = tid & 63;
  int l15 = lane & 15, l4 = lane >> 4;
  int wr = w >> 1, wc = w & 1;
  int o0 = ntile * 128;
  const unsigned hrow = (unsigned)hchunk * 2;

  unsigned offA[4], offB[4];
#pragma unroll
  for (int q = 0; q < 4; ++q) {
    int d   = q * 4096 + w * 1024 + lane * 16;
    int row = d >> 7;
    int bs  = (d & 127) ^ ((row & 7) << 4);
    offA[q] = (unsigned)min(base + row, N_TOK - 1) * hrow + bs;
    offB[q] = (unsigned)(e * O_DIM + o0 + row) * (H_DIM * 2) + (unsigned)ch * hchunk * 2 + bs;
  }

  f32x4 acc[4][4];
#pragma unroll
  for (int a = 0; a < 4; ++a)
#pragma unroll
    for (int b = 0; b < 4; ++b) acc[a][b] = (f32x4){0.f, 0.f, 0.f, 0.f};

#define STAGE2(buf, kstep) do {                                              \
    unsigned kb = (unsigned)(kstep) * 128u;                                  \
    unsigned char* da = lds + (unsigned)(buf) * 16384u;                      \
    unsigned char* db = lds + 32768u + (unsigned)(buf) * 16384u;             \
    _Pragma("unroll")                                                        \
    for (int q = 0; q < 4; ++q) {                                            \
      gll16((const char*)Hperm + offA[q] + kb, da + q * 4096 + w * 1024);    \
      gll16((const char*)W2T   + offB[q] + kb, db + q * 4096 + w * 1024);    \
    }                                                                        \
  } while (0)

#define COMPUTE2(buf) do {                                                   \
    const unsigned char* A = lds + (unsigned)(buf) * 16384u;                 \
    const unsigned char* B = lds + 32768u + (unsigned)(buf) * 16384u;        \
    __builtin_amdgcn_s_setprio(1);                                           \
    _Pragma("unroll")                                                        \
    for (int ks = 0; ks < 2; ++ks) {                                         \
      int kb = ks * 64 + l4 * 16;                                            \
      bf16x8 bfr[4];                                                         \
      _Pragma("unroll")                                                      \
      for (int nf = 0; nf < 4; ++nf) {                                       \
        int n = wc * 64 + nf * 16 + l15;                                     \
        bfr[nf] = *(const bf16x8*)(B + n * 128 + (kb ^ ((n & 7) << 4)));     \
      }                                                                      \
      _Pragma("unroll")                                                      \
      for (int mf = 0; mf < 4; ++mf) {                                       \
        int m = wr * 64 + mf * 16 + l15;                                     \
        bf16x8 af = *(const bf16x8*)(A + m * 128 + (kb ^ ((m & 7) << 4)));   \
        _Pragma("unroll")                                                    \
        for (int nf = 0; nf < 4; ++nf)                                       \
          acc[mf][nf] = __builtin_amdgcn_mfma_f32_16x16x32_bf16(af, bfr[nf], acc[mf][nf], 0, 0, 0); \
      }                                                                      \
    }                                                                        \
    __builtin_amdgcn_s_setprio(0);                                           \
  } while (0)

  const int NK = hchunk / 64;  // 32 at hchunk=2048
  STAGE2(0, 0);
  WAITV0;
  BAR();
  for (int t = 0; t < NK; ++t) {
    if (t + 1 < NK) { STAGE2((t + 1) & 1, t + 1); __builtin_amdgcn_sched_barrier(0); }
    COMPUTE2(t & 1);
    WAITV0;
    BAR();
  }

  // epilogue: scatter fp32 rows (64B contiguous per 16 lanes), bias on first chunk
#pragma unroll
  for (int nf = 0; nf < 4; ++nf) {
    int o = o0 + wc * 64 + nf * 16 + l15;
    float bv = b2[(size_t)e * O_DIM + o];
#pragma unroll
    for (int mf = 0; mf < 4; ++mf) {
#pragma unroll
      for (int j = 0; j < 4; ++j) {
        int row = wr * 64 + mf * 16 + l4 * 4 + j;
        if (row < mvalid) {
          int tok = idx_list[base + row];
          float* p = out + (size_t)tok * O_DIM + o;
          if (accumulate) *p = *p + acc[mf][nf][j];
          else            *p = acc[mf][nf][j] + bv;
        }
      }
    }
  }
#undef STAGE2
#undef COMPUTE2
}

// ---------------- launch ----------------
extern "C" void kernel_launch(void* const* d_in, const int* in_sizes, int n_in,
                              void* d_out, int out_size, void* d_ws, size_t ws_size,
                              hipStream_t stream) {
  const float* x  = (const float*)d_in[0];
  const float* Wr = (const float*)d_in[1];
  const float* br = (const float*)d_in[2];
  const float* W1 = (const float*)d_in[3];
  const float* b1 = (const float*)d_in[4];
  const float* W2 = (const float*)d_in[5];
  const float* b2 = (const float*)d_in[6];
  float* out = (float*)d_out;

  char* ws = (char*)d_ws;
  int*  counts    = (int*)(ws + 0);
  int*  offsets   = (int*)(ws + 64);
  int*  cursor    = (int*)(ws + 128);
  int2* table     = (int2*)(ws + 256);                 // 272*8 = 2176 B
  int*  expert_id = (int*)(ws + 4096);                 // 128 KB
  int*  idx_list  = (int*)(ws + 4096 + N_TOK * 4);     // 128 KB
  size_t off = 4096 + 2 * (size_t)N_TOK * 4;
  unsigned short* xbf = (unsigned short*)(ws + off);   // 32 MB
  off += (size_t)N_TOK * D_IN * 2;
  unsigned short* W1T = (unsigned short*)(ws + off);   // 16 MB
  off += (size_t)N_EXP * H_DIM * D_IN * 2;
  unsigned short* W2T = (unsigned short*)(ws + off);   // 16 MB
  off += (size_t)N_EXP * H_DIM * O_DIM * 2;
  unsigned short* Hperm = (unsigned short*)(ws + off);

  // largest H-chunk that fits remaining workspace (256-col floor)
  int hchunk = 2048;
  while (hchunk > 256 && off + (size_t)N_TOK * hchunk * 2 > ws_size) hchunk >>= 1;
  int nch = H_DIM / hchunk;
  int nt1 = hchunk / 128;

  k_init<<<1, 64, 0, stream>>>(counts);
  k_transpose<<<dim3(256, N_EXP), 256, 0, stream>>>(W1, W1T, D_IN, H_DIM);
  k_transpose<<<dim3(256, N_EXP), 256, 0, stream>>>(W2, W2T, H_DIM, O_DIM);
  k_router<<<N_TOK / 4, 256, 0, stream>>>(x, Wr, br, expert_id, xbf);
  k_count<<<N_TOK / 1024, 1024, 0, stream>>>(expert_id, counts);
  k_scan<<<1, 512, 0, stream>>>(counts, offsets, cursor, table);
  k_scatter<<<N_TOK / 512, 512, 0, stream>>>(expert_id, cursor, idx_list);

  for (int ch = 0; ch < nch; ++ch) {
    k_gemm1<<<8 * TPX * nt1, 256, 0, stream>>>(xbf, W1T, b1, counts, offsets,
                                               table, idx_list, Hperm, nt1, ch, hchunk);
    k_gemm2<<<8 * TPX * 4, 256, 0, stream>>>(Hperm, W2T, b2, counts, offsets,
                                             table, idx_list, out, ch, hchunk, ch > 0);
  }
}

// Round 8
// 332.280 us; speedup vs baseline: 5.0237x; 1.0651x over previous
//
#include <hip/hip_runtime.h>
#include <stdint.h>

#define N_TOK 32768
#define D_IN  512
#define H_DIM 2048
#define O_DIM 512
#define N_EXP 8
// tiles: M=128 rows of permuted tokens. sum ceil(cnt/128) <= 256+7; pad to 272 = 8 XCDs * 34
#define NTILES 272
#define TPX    34

typedef __bf16 bf16x8 __attribute__((ext_vector_type(8)));
typedef float  f32x4  __attribute__((ext_vector_type(4)));
typedef unsigned int u32x4 __attribute__((ext_vector_type(4)));

struct alignas(8) us4 { unsigned short x, y, z, w; };

#define FENCE() asm volatile("" ::: "memory")
#define BAR()   do { FENCE(); __builtin_amdgcn_s_barrier(); FENCE(); } while (0)
#define WAITV0  asm volatile("s_waitcnt vmcnt(0)" ::: "memory")

__device__ __forceinline__ unsigned short f2bf(float f) {
  union { float f; unsigned u; } v; v.f = f;
  unsigned r = v.u + 0x7FFFu + ((v.u >> 16) & 1u);  // round-to-nearest-even
  return (unsigned short)(r >> 16);
}

// async global->LDS, 16B/lane; LDS dest = wave-uniform base + lane*16 (HW)
__device__ __forceinline__ void gll16(const void* src, void* lds_dst) {
  __builtin_amdgcn_global_load_lds(
      (const __attribute__((address_space(1))) void*)src,
      (__attribute__((address_space(3))) void*)lds_dst, 16, 0, 0);
}

// ---------------- init ----------------
__global__ void k_init(int* counts) {
  if (threadIdx.x < N_EXP) counts[threadIdx.x] = 0;
}

// ---------------- weight convert + transpose to bf16: W (E,R,C) f32 -> WT (E,C,R) bf16 ----------------
__global__ void k_transpose(const float* __restrict__ W, unsigned short* __restrict__ WT,
                            int R, int C) {
  __shared__ unsigned short tile[64][72];
  int e = blockIdx.y;
  const float* src = W + (size_t)e * R * C;
  unsigned short* dst = WT + (size_t)e * R * C;
  int tilesC = C >> 6;
  int tc = (blockIdx.x % tilesC) << 6;
  int tr = (blockIdx.x / tilesC) << 6;
  int tid = threadIdx.x;
  int rq = tid >> 4;
  int cq = tid & 15;
#pragma unroll
  for (int q = 0; q < 4; ++q) {
    int r = q * 16 + rq;
    float4 v = *(const float4*)(src + (size_t)(tr + r) * C + tc + cq * 4);
    us4 b;
    b.x = f2bf(v.x); b.y = f2bf(v.y); b.z = f2bf(v.z); b.w = f2bf(v.w);
    *(us4*)&tile[r][cq * 4] = b;
  }
  __syncthreads();
#pragma unroll
  for (int q = 0; q < 4; ++q) {
    int cc = q * 16 + rq;
    int rr = cq * 4;
    us4 o;
    o.x = tile[rr + 0][cc]; o.y = tile[rr + 1][cc];
    o.z = tile[rr + 2][cc]; o.w = tile[rr + 3][cc];
    *(us4*)(dst + (size_t)(tc + cc) * R + tr + rr) = o;
  }
}

// ---------------- router (fp32) + fused x -> bf16 cast; NO atomics ----------------
__global__ void k_router(const float* __restrict__ x, const float* __restrict__ Wr,
                         const float* __restrict__ br, int* __restrict__ expert_id,
                         unsigned short* __restrict__ xbf) {
  int token = blockIdx.x * 4 + (threadIdx.x >> 6);
  int lane  = threadIdx.x & 63;
  const float* xr = x + (size_t)token * D_IN;
  float acc[N_EXP];
#pragma unroll
  for (int e = 0; e < N_EXP; ++e) acc[e] = 0.f;
#pragma unroll
  for (int j = 0; j < 2; ++j) {
    int i0 = lane * 8 + j * 4;
    float4 xv = *(const float4*)(xr + i0);
    us4 bb;
    bb.x = f2bf(xv.x); bb.y = f2bf(xv.y); bb.z = f2bf(xv.z); bb.w = f2bf(xv.w);
    *(us4*)(xbf + (size_t)token * D_IN + i0) = bb;
    float xs[4] = {xv.x, xv.y, xv.z, xv.w};
#pragma unroll
    for (int u = 0; u < 4; ++u) {
      const float4* wr = (const float4*)(Wr + (size_t)(i0 + u) * N_EXP);
      float4 w0 = wr[0], w1 = wr[1];
      acc[0] += xs[u] * w0.x; acc[1] += xs[u] * w0.y;
      acc[2] += xs[u] * w0.z; acc[3] += xs[u] * w0.w;
      acc[4] += xs[u] * w1.x; acc[5] += xs[u] * w1.y;
      acc[6] += xs[u] * w1.z; acc[7] += xs[u] * w1.w;
    }
  }
#pragma unroll
  for (int off = 32; off > 0; off >>= 1) {
#pragma unroll
    for (int e = 0; e < N_EXP; ++e) acc[e] += __shfl_xor(acc[e], off, 64);
  }
  if (lane == 0) {
    float best = acc[0] + br[0]; int bi = 0;
#pragma unroll
    for (int e = 1; e < N_EXP; ++e) {
      float v = acc[e] + br[e];
      if (v > best) { best = v; bi = e; }   // first max wins (matches top_k)
    }
    expert_id[token] = bi;
  }
}

// ---------------- count: LDS histogram ----------------
__global__ void k_count(const int* __restrict__ expert_id, int* __restrict__ counts) {
  __shared__ int lcnt[N_EXP];
  int tid = threadIdx.x;
  if (tid < N_EXP) lcnt[tid] = 0;
  __syncthreads();
  int e = expert_id[blockIdx.x * 1024 + tid];
  atomicAdd(&lcnt[e], 1);
  __syncthreads();
  if (tid < N_EXP) atomicAdd(&counts[tid], lcnt[tid]);
}

// ---------------- scan: offsets + cursors + expert-major 128-row tile table ----------------
__global__ void k_scan(const int* __restrict__ counts, int* __restrict__ offsets,
                       int* __restrict__ cursor, int2* __restrict__ table) {
  int i = threadIdx.x;   // 512 threads
  int s = 0, ts = 0, myexp = -1, myt = -1;
#pragma unroll
  for (int e = 0; e < N_EXP; ++e) {
    int c = counts[e];
    int tc = (c + 127) >> 7;
    if (i == e) { offsets[e] = s; cursor[e] = s; }
    if (i >= ts && i < ts + tc) { myexp = e; myt = i - ts; }
    s += c; ts += tc;
  }
  if (i < NTILES) table[i] = make_int2(myexp, myt);
}

// ---------------- scatter: LDS histogram, one block-atomic per expert ----------------
__global__ void k_scatter(const int* __restrict__ expert_id, int* __restrict__ cursor,
                          int* __restrict__ idx_list) {
  __shared__ int lcnt[N_EXP], lbase[N_EXP];
  int tid = threadIdx.x;
  int i = blockIdx.x * 512 + tid;
  if (tid < N_EXP) lcnt[tid] = 0;
  __syncthreads();
  int e = expert_id[i];
  int lpos = atomicAdd(&lcnt[e], 1);
  __syncthreads();
  if (tid < N_EXP) lbase[tid] = atomicAdd(&cursor[tid], lcnt[tid]);
  __syncthreads();
  idx_list[lbase[e] + lpos] = i;
}

// ========== m97-replica GEMM core: 128x128 tile, BK=64, 4 waves, SINGLE 32KB LDS buffer ==========
// 4 blocks/CU; latency hiding via inter-block overlap (m114). stage -> vmcnt(0) -> bar -> mfma -> bar.

// ---------------- GEMM1: Hperm = relu(Xg @ W1T^T + b1) ----------------
__launch_bounds__(256, 4)
__global__ void k_gemm1(const unsigned short* __restrict__ xbf,
                        const unsigned short* __restrict__ W1T,   // (E, H, D) bf16
                        const float* __restrict__ b1,
                        const int* __restrict__ counts, const int* __restrict__ offsets,
                        const int2* __restrict__ table, const int* __restrict__ idx_list,
                        unsigned short* __restrict__ Hperm,       // (N_TOK, hchunk) bf16
                        int nt1, int ch, int hchunk) {
  int xcd = blockIdx.x & 7;
  int s   = blockIdx.x >> 3;
  int tile  = xcd * TPX + s / nt1;   // XCD owns a CONTIGUOUS run of tiles -> 1 expert panel in L2
  int ntile = s % nt1;
  int2 et = table[tile];
  int e = et.x;
  if (e < 0) return;
  int base   = offsets[e] + et.y * 128;
  int mvalid = min(128, counts[e] - et.y * 128);

  __shared__ __align__(16) unsigned char lds[32768];  // A @0 (16K), B @16K; epilogue bounce reuses all

  int tid = threadIdx.x, w = tid >> 6, lane = tid & 63;
  int l15 = lane & 15, l4 = lane >> 4;
  int wr = w >> 1, wc = w & 1;
  int n0 = ch * hchunk + ntile * 128;   // global H col base

  unsigned offA[4], offB[4];
#pragma unroll
  for (int q = 0; q < 4; ++q) {
    int d   = q * 4096 + w * 1024 + lane * 16;   // linear dest byte in 16KB tile
    int row = d >> 7;
    int bs  = (d & 127) ^ ((row & 7) << 4);      // inverse-swizzled source byte
    int tok = idx_list[base + min(row, mvalid - 1)];
    offA[q] = (unsigned)tok * (D_IN * 2) + bs;
    offB[q] = (unsigned)(e * H_DIM + n0 + row) * (D_IN * 2) + bs;
  }

  f32x4 acc[4][4];
#pragma unroll
  for (int a = 0; a < 4; ++a)
#pragma unroll
    for (int b = 0; b < 4; ++b) acc[a][b] = (f32x4){0.f, 0.f, 0.f, 0.f};

#define STAGE1(kstep) do {                                                   \
    unsigned kb = (unsigned)(kstep) * 128u;                                  \
    _Pragma("unroll")                                                        \
    for (int q = 0; q < 4; ++q) {                                            \
      gll16((const char*)xbf + offA[q] + kb, lds + q * 4096 + w * 1024);     \
      gll16((const char*)W1T + offB[q] + kb, lds + 16384 + q * 4096 + w * 1024); \
    }                                                                        \
  } while (0)

#define COMPUTE1() do {                                                      \
    const unsigned char* A = lds;                                            \
    const unsigned char* B = lds + 16384;                                    \
    __builtin_amdgcn_s_setprio(1);                                           \
    _Pragma("unroll")                                                        \
    for (int ks = 0; ks < 2; ++ks) {                                         \
      int kb = ks * 64 + l4 * 16;                                            \
      bf16x8 bfr[4];                                                         \
      _Pragma("unroll")                                                      \
      for (int nf = 0; nf < 4; ++nf) {                                       \
        int n = wc * 64 + nf * 16 + l15;                                     \
        bfr[nf] = *(const bf16x8*)(B + n * 128 + (kb ^ ((n & 7) << 4)));     \
      }                                                                      \
      _Pragma("unroll")                                                      \
      for (int mf = 0; mf < 4; ++mf) {                                       \
        int m = wr * 64 + mf * 16 + l15;                                     \
        bf16x8 af = *(const bf16x8*)(A + m * 128 + (kb ^ ((m & 7) << 4)));   \
        _Pragma("unroll")                                                    \
        for (int nf = 0; nf < 4; ++nf)                                       \
          acc[mf][nf] = __builtin_amdgcn_mfma_f32_16x16x32_bf16(af, bfr[nf], acc[mf][nf], 0, 0, 0); \
      }                                                                      \
    }                                                                        \
    __builtin_amdgcn_s_setprio(0);                                           \
  } while (0)

  const int NK = D_IN / 64;  // 8
  for (int t = 0; t < NK; ++t) {
    STAGE1(t);
    WAITV0;
    BAR();
    COMPUTE1();
    BAR();
  }

  // epilogue: bias+relu -> bf16 LDS bounce (128 rows x 256 B, XOR swz) -> coalesced stores
#pragma unroll
  for (int nf = 0; nf < 4; ++nf) {
    int col = wc * 64 + nf * 16 + l15;
    float bv = b1[(size_t)e * H_DIM + n0 + col];
#pragma unroll
    for (int mf = 0; mf < 4; ++mf) {
#pragma unroll
      for (int j = 0; j < 4; ++j) {
        int row = wr * 64 + mf * 16 + l4 * 4 + j;
        float v = fmaxf(acc[mf][nf][j] + bv, 0.f);
        *(unsigned short*)(lds + row * 256 + ((col * 2) ^ ((row & 7) << 4))) = f2bf(v);
      }
    }
  }
  BAR();
  {
    int row = tid >> 1;          // 0..127
    int seg = (tid & 1) * 128;   // 128B half of the 256B row
    if (row < mvalid) {
      int swz = (row & 7) << 4;
      char* gdst = (char*)Hperm + ((size_t)(base + row) * hchunk + ntile * 128) * 2 + seg;
      const unsigned char* lsrc = lds + row * 256;
#pragma unroll
      for (int i = 0; i < 8; ++i) {
        u32x4 v = *(const u32x4*)(lsrc + ((seg + i * 16) ^ swz));
        *(u32x4*)(gdst + i * 16) = v;
      }
    }
  }
#undef STAGE1
#undef COMPUTE1
}

// ---------------- GEMM2: out = Hperm @ W2T^T (+ b2) ----------------
__launch_bounds__(256, 4)
__global__ void k_gemm2(const unsigned short* __restrict__ Hperm,  // (N_TOK, hchunk) bf16
                        const unsigned short* __restrict__ W2T,    // (E, O, H) bf16
                        const float* __restrict__ b2,
                        const int* __restrict__ counts, const int* __restrict__ offsets,
                        const int2* __restrict__ table, const int* __restrict__ idx_list,
                        float* __restrict__ out,
                        int ch, int hchunk, int accumulate) {
  int xcd = blockIdx.x & 7;
  int s   = blockIdx.x >> 3;
  int tile  = xcd * TPX + (s >> 2);   // contiguous tile run per XCD
  int ntile = s & 3;
  int2 et = table[tile];
  int e = et.x;
  if (e < 0) return;
  int base   = offsets[e] + et.y * 128;
  int mvalid = min(128, counts[e] - et.y * 128);

  __shared__ __align__(16) unsigned char lds[32768];

  int tid = threadIdx.x, w = tid >> 6, lane = tid & 63;
  int l15 = lane & 15, l4 = lane >> 4;
  int wr = w >> 1, wc = w & 1;
  int o0 = ntile * 128;
  const unsigned hrow = (unsigned)hchunk * 2;

  unsigned offA[4], offB[4];
#pragma unroll
  for (int q = 0; q < 4; ++q) {
    int d   = q * 4096 + w * 1024 + lane * 16;
    int row = d >> 7;
    int bs  = (d & 127) ^ ((row & 7) << 4);
    offA[q] = (unsigned)min(base + row, N_TOK - 1) * hrow + bs;
    offB[q] = (unsigned)(e * O_DIM + o0 + row) * (H_DIM * 2) + (unsigned)ch * hchunk * 2 + bs;
  }

  f32x4 acc[4][4];
#pragma unroll
  for (int a = 0; a < 4; ++a)
#pragma unroll
    for (int b = 0; b < 4; ++b) acc[a][b] = (f32x4){0.f, 0.f, 0.f, 0.f};

#define STAGE2(kstep) do {                                                   \
    unsigned kb = (unsigned)(kstep) * 128u;                                  \
    _Pragma("unroll")                                                        \
    for (int q = 0; q < 4; ++q) {                                            \
      gll16((const char*)Hperm + offA[q] + kb, lds + q * 4096 + w * 1024);   \
      gll16((const char*)W2T   + offB[q] + kb, lds + 16384 + q * 4096 + w * 1024); \
    }                                                                        \
  } while (0)

#define COMPUTE2() do {                                                      \
    const unsigned char* A = lds;                                            \
    const unsigned char* B = lds + 16384;                                    \
    __builtin_amdgcn_s_setprio(1);                                           \
    _Pragma("unroll")                                                        \
    for (int ks = 0; ks < 2; ++ks) {                                         \
      int kb = ks * 64 + l4 * 16;                                            \
      bf16x8 bfr[4];                                                         \
      _Pragma("unroll")                                                      \
      for (int nf = 0; nf < 4; ++nf) {                                       \
        int n = wc * 64 + nf * 16 + l15;                                     \
        bfr[nf] = *(const bf16x8*)(B + n * 128 + (kb ^ ((n & 7) << 4)));     \
      }                                                                      \
      _Pragma("unroll")                                                      \
      for (int mf = 0; mf < 4; ++mf) {                                       \
        int m = wr * 64 + mf * 16 + l15;                                     \
        bf16x8 af = *(const bf16x8*)(A + m * 128 + (kb ^ ((m & 7) << 4)));   \
        _Pragma("unroll")                                                    \
        for (int nf = 0; nf < 4; ++nf)                                       \
          acc[mf][nf] = __builtin_amdgcn_mfma_f32_16x16x32_bf16(af, bfr[nf], acc[mf][nf], 0, 0, 0); \
      }                                                                      \
    }                                                                        \
    __builtin_amdgcn_s_setprio(0);                                           \
  } while (0)

  const int NK = hchunk / 64;  // 32 at hchunk=2048
  for (int t = 0; t < NK; ++t) {
    STAGE2(t);
    WAITV0;
    BAR();
    COMPUTE2();
    BAR();
  }

  // epilogue: scatter fp32 rows (64B contiguous per 16 lanes), bias on first chunk
#pragma unroll
  for (int nf = 0; nf < 4; ++nf) {
    int o = o0 + wc * 64 + nf * 16 + l15;
    float bv = b2[(size_t)e * O_DIM + o];
#pragma unroll
    for (int mf = 0; mf < 4; ++mf) {
#pragma unroll
      for (int j = 0; j < 4; ++j) {
        int row = wr * 64 + mf * 16 + l4 * 4 + j;
        if (row < mvalid) {
          int tok = idx_list[base + row];
          float* p = out + (size_t)tok * O_DIM + o;
          if (accumulate) *p = *p + acc[mf][nf][j];
          else            *p = acc[mf][nf][j] + bv;
        }
      }
    }
  }
#undef STAGE2
#undef COMPUTE2
}

// ---------------- launch ----------------
extern "C" void kernel_launch(void* const* d_in, const int* in_sizes, int n_in,
                              void* d_out, int out_size, void* d_ws, size_t ws_size,
                              hipStream_t stream) {
  const float* x  = (const float*)d_in[0];
  const float* Wr = (const float*)d_in[1];
  const float* br = (const float*)d_in[2];
  const float* W1 = (const float*)d_in[3];
  const float* b1 = (const float*)d_in[4];
  const float* W2 = (const float*)d_in[5];
  const float* b2 = (const float*)d_in[6];
  float* out = (float*)d_out;

  char* ws = (char*)d_ws;
  int*  counts    = (int*)(ws + 0);
  int*  offsets   = (int*)(ws + 64);
  int*  cursor    = (int*)(ws + 128);
  int2* table     = (int2*)(ws + 256);                 // 272*8 = 2176 B
  int*  expert_id = (int*)(ws + 4096);                 // 128 KB
  int*  idx_list  = (int*)(ws + 4096 + N_TOK * 4);     // 128 KB
  size_t off = 4096 + 2 * (size_t)N_TOK * 4;
  unsigned short* xbf = (unsigned short*)(ws + off);   // 32 MB
  off += (size_t)N_TOK * D_IN * 2;
  unsigned short* W1T = (unsigned short*)(ws + off);   // 16 MB
  off += (size_t)N_EXP * H_DIM * D_IN * 2;
  unsigned short* W2T = (unsigned short*)(ws + off);   // 16 MB
  off += (size_t)N_EXP * H_DIM * O_DIM * 2;
  unsigned short* Hperm = (unsigned short*)(ws + off);

  // largest H-chunk that fits remaining workspace (256-col floor)
  int hchunk = 2048;
  while (hchunk > 256 && off + (size_t)N_TOK * hchunk * 2 > ws_size) hchunk >>= 1;
  int nch = H_DIM / hchunk;
  int nt1 = hchunk / 128;

  k_init<<<1, 64, 0, stream>>>(counts);
  k_transpose<<<dim3(256, N_EXP), 256, 0, stream>>>(W1, W1T, D_IN, H_DIM);
  k_transpose<<<dim3(256, N_EXP), 256, 0, stream>>>(W2, W2T, H_DIM, O_DIM);
  k_router<<<N_TOK / 4, 256, 0, stream>>>(x, Wr, br, expert_id, xbf);
  k_count<<<N_TOK / 1024, 1024, 0, stream>>>(expert_id, counts);
  k_scan<<<1, 512, 0, stream>>>(counts, offsets, cursor, table);
  k_scatter<<<N_TOK / 512, 512, 0, stream>>>(expert_id, cursor, idx_list);

  for (int ch = 0; ch < nch; ++ch) {
    k_gemm1<<<8 * TPX * nt1, 256, 0, stream>>>(xbf, W1T, b1, counts, offsets,
                                               table, idx_list, Hperm, nt1, ch, hchunk);
    k_gemm2<<<8 * TPX * 4, 256, 0, stream>>>(Hperm, W2T, b2, counts, offsets,
                                             table, idx_list, out, ch, hchunk, ch > 0);
  }
}